// Round 29
// baseline (392.572 us; speedup 1.0000x reference)
//
#include <hip/hip_runtime.h>
#include <math.h>

#define TOK   8192
#define DIM   256
#define NH    8
#define HDIM  32
#define FFD   1024
#define NE    8
#define NL    2
#define NOUT  1000
#define NSLOT 16384   // TOK*2

typedef unsigned int uint;
typedef unsigned short ushort;
typedef __attribute__((ext_vector_type(8))) short short8;
typedef __attribute__((ext_vector_type(4))) float f32x4;

// ---------------- workspace layout (float units) ----------------
#define WS_X     ((size_t)0)
#define WS_LN    (WS_X    + (size_t)TOK*DIM)
#define WS_QKV   (WS_LN   + (size_t)TOK*DIM)
#define WS_H     (WS_QKV  + (size_t)TOK*3*DIM)
#define WS_SOUT  (WS_H    + (size_t)NSLOT*256)
#define WS_GV    (WS_SOUT + (size_t)NSLOT*256)
#define WS_PP    (WS_GV   + (size_t)TOK*2)
#define WS_POOL  (WS_PP   + (size_t)8*32*256)
#define WS_INT   (WS_POOL + (size_t)8*256)
#define WS_U16   (WS_INT  + (size_t)54144)
#define WS_BIG   (WS_U16  + (size_t)2359296)

// int region layout (int32 indices)
#define IB_COUNTS   0
#define IB_NTILES   8
#define IB_OFFS     16
#define IB_CURS     24
#define IB_TILE_E   32
#define IB_TILE_R0  320
#define IB_TILE_RE  608
#define IB_GIDX     896    // [TOK*2]
#define IB_SPOS     17280  // [TOK*2]
#define IB_STOK     33664  // [NSLOT]
#define IB_BLKC     50048  // [256*8]
#define IB_BLKB     52096  // [256*8]

// fast erf (Abramowitz-Stegun 7.1.26, |err| <= 1.5e-7) — error far below the
// bf16 rounding (2e-3 rel) applied to h right after.
__device__ __forceinline__ float gelu_exact(float v) {
    float z = v * 0.70710678118654752f;
    float s = fabsf(z);
    float t = __builtin_amdgcn_rcpf(1.0f + 0.3275911f * s);
    float p = ((((1.061405429f * t - 1.453152027f) * t + 1.421413741f) * t
                - 0.284496736f) * t + 0.254829592f) * t;
    float r = 1.0f - p * __expf(-s * s);
    float er = (z < 0.0f) ? -r : r;
    return 0.5f * v * (1.0f + er);
}

__device__ __forceinline__ ushort rnd_bf16(float x) {
    uint u = __float_as_uint(x);
    return (ushort)((u + 0x7FFFu + ((u >> 16) & 1u)) >> 16);
}

__device__ __forceinline__ void split2(float x, ushort& h, ushort& lo) {
    uint u = __float_as_uint(x);
    uint hh = (u + 0x7FFFu + ((u >> 16) & 1u)) >> 16;
    h = (ushort)hh;
    float hf = __uint_as_float(hh << 16);
    float l = x - hf;
    uint ul = __float_as_uint(l);
    lo = (ushort)((ul + 0x7FFFu + ((ul >> 16) & 1u)) >> 16);
}

// async global->LDS 16B: dest = wave-uniform base + lane*16 (linear); source per-lane.
__device__ __forceinline__ void gld16(const ushort* g, ushort* l) {
    __builtin_amdgcn_global_load_lds(
        (const __attribute__((address_space(1))) uint*)g,
        (__attribute__((address_space(3))) uint*)l, 16, 0, 0);
}

// XCD-aware decode: all NC col-blocks of a tile share bid%8 -> same XCD L2.
// Bijective for NT % 8 == 0. HW round-robins XCD by hardware block id.
__device__ __forceinline__ void xcd_map(int bid, int NC, int& t, int& j) {
    int g = bid >> 3;
    t = (bid & 7) + 8 * (g / NC);
    j = g % NC;
}

// ---------------- LayerNorm -> bf16 (hi-only) output (+optional f32) ----------------
template<bool WF32>
__global__ __launch_bounds__(256) void ln_split(const float* __restrict__ x,
                                                float* __restrict__ out,
                                                ushort* __restrict__ ohi,
                                                const float* __restrict__ g,
                                                const float* __restrict__ b) {
    int wave = threadIdx.x >> 6;
    int lane = threadIdx.x & 63;
    int t = blockIdx.x * 4 + wave;
    const float* xp = x + (size_t)t * DIM;
    float4 v = *(const float4*)&xp[lane * 4];
    float s = v.x + v.y + v.z + v.w;
    #pragma unroll
    for (int off = 32; off; off >>= 1) s += __shfl_xor(s, off);
    float mean = s * (1.0f / 256.0f);
    float dx = v.x - mean, dy = v.y - mean, dz = v.z - mean, dw = v.w - mean;
    float vs = dx * dx + dy * dy + dz * dz + dw * dw;
    #pragma unroll
    for (int off = 32; off; off >>= 1) vs += __shfl_xor(vs, off);
    float inv = rsqrtf(vs * (1.0f / 256.0f) + 1e-5f);
    float4 gg = *(const float4*)&g[lane * 4];
    float4 bb = *(const float4*)&b[lane * 4];
    float o0 = dx * inv * gg.x + bb.x;
    float o1 = dy * inv * gg.y + bb.y;
    float o2 = dz * inv * gg.z + bb.z;
    float o3 = dw * inv * gg.w + bb.w;
    size_t idx = (size_t)t * DIM + lane * 4;
    if (WF32) {
        float4 o; o.x = o0; o.y = o1; o.z = o2; o.w = o3;
        *(float4*)&out[idx] = o;
    }
    uint2 ph;
    ph.x = (uint)rnd_bf16(o0) | ((uint)rnd_bf16(o1) << 16);
    ph.y = (uint)rnd_bf16(o2) | ((uint)rnd_bf16(o3) << 16);
    *(uint2*)&ohi[idx] = ph;
}

// ---------------- split+transpose weights (WLO=false: hi only) ----------------
template<bool WLO>
__global__ __launch_bounds__(256) void split_transpose(const float* __restrict__ src,
                                                       ushort* __restrict__ dhi,
                                                       ushort* __restrict__ dlo,
                                                       int K, int N) {
    int z = blockIdx.z;
    const float* s = src + (size_t)z * K * N;
    ushort* th = dhi + (size_t)z * K * N;
    ushort* tl = dlo + (size_t)z * K * N;
    __shared__ float tile[32][33];
    int k0 = blockIdx.x * 32, n0 = blockIdx.y * 32;
    int tx = threadIdx.x & 31, ty = threadIdx.x >> 5;
    #pragma unroll
    for (int i = 0; i < 4; ++i) {
        int k = k0 + ty + i * 8;
        tile[ty + i * 8][tx] = s[(size_t)k * N + n0 + tx];
    }
    __syncthreads();
    #pragma unroll
    for (int i = 0; i < 4; ++i) {
        int n = n0 + ty + i * 8;
        float v = tile[tx][ty + i * 8];
        ushort h, lo;
        split2(v, h, lo);
        th[(size_t)n * K + k0 + tx] = h;
        if (WLO) tl[(size_t)n * K + k0 + tx] = lo;
    }
}

// ============ 128x128 GEMM core, BK=64, all hi-only, XCD-swizzled 1D grid ============
// MODE 0=f32 out, 1=f32+residual, 3=bf16 out. Grid = NT*NC blocks, NT%8==0, NC = N/128.
// Per k-step: 32 MFMA, 8 staging issues (vs 16/6 at 128x64).

template<int MODE>
__global__ __launch_bounds__(256) void mfma_dense128x128(const ushort* __restrict__ Ah,
                                                         const ushort* __restrict__ Bh,
                                                         const float* __restrict__ bias,
                                                         float* __restrict__ C,
                                                         ushort* __restrict__ Chi, int N, int NC) {
    __shared__ ushort LAh[128][64], LBh[128][64];
    int tT, tJ;
    xcd_map(blockIdx.x, NC, tT, tJ);
    int tid = threadIdx.x;
    int w = tid >> 6, l = tid & 63, c = l & 15, G = l >> 4;
    int row0 = tT * 128, col0 = tJ * 128;
    int lr = l >> 3, sd = l & 7;
    size_t gaA[4]; ushort* dA[4];
    size_t gbB[4]; ushort* dB[4];
    #pragma unroll
    for (int i = 0; i < 4; ++i) {
        int r = i * 32 + w * 8 + lr;
        gaA[i] = (size_t)(row0 + r) * 256 + ((sd ^ (r & 7)) << 3);
        dA[i] = &LAh[i * 32 + w * 8][0];
        gbB[i] = (size_t)(col0 + r) * 256 + ((sd ^ (r & 7)) << 3);
        dB[i] = &LBh[i * 32 + w * 8][0];
    }
    f32x4 acc[2][8] = {};
    for (int k0 = 0; k0 < 256; k0 += 64) {
        #pragma unroll
        for (int i = 0; i < 4; ++i) gld16(&Ah[gaA[i] + k0], dA[i]);
        #pragma unroll
        for (int i = 0; i < 4; ++i) gld16(&Bh[gbB[i] + k0], dB[i]);
        __syncthreads();
        #pragma unroll
        for (int s = 0; s < 2; ++s) {
            int ar = w * 32 + c;
            short8 a_h[2];
            #pragma unroll
            for (int i = 0; i < 2; ++i) {
                int r = ar + i * 16;
                int sg = (((s << 2) | G) ^ (r & 7)) << 3;
                a_h[i] = *(const short8*)&LAh[r][sg];
            }
            #pragma unroll
            for (int j = 0; j < 8; ++j) {
                int r = j * 16 + c;
                int sg = (((s << 2) | G) ^ (r & 7)) << 3;
                short8 b_h = *(const short8*)&LBh[r][sg];
                #pragma unroll
                for (int i = 0; i < 2; ++i) {
                    acc[i][j] = __builtin_amdgcn_mfma_f32_16x16x32_bf16(a_h[i], b_h, acc[i][j], 0, 0, 0);
                }
            }
        }
        __syncthreads();
    }
    int rbase = row0 + w * 32 + G * 4;
    #pragma unroll
    for (int i = 0; i < 2; ++i) {
        #pragma unroll
        for (int j = 0; j < 8; ++j) {
            int gc = col0 + j * 16 + c;
            float bv = bias[gc];
            #pragma unroll
            for (int rr = 0; rr < 4; ++rr) {
                int grow = rbase + i * 16 + rr;
                size_t idx = (size_t)grow * N + gc;
                float v = acc[i][j][rr] + bv;
                if (MODE == 1) v += C[idx];
                if (MODE == 3) {
                    Chi[idx] = rnd_bf16(v);
                } else {
                    C[idx] = v;
                }
            }
        }
    }
}

// ---------------- V transpose (hi-only) ----------------
__global__ __launch_bounds__(256) void vt_kernel(const ushort* __restrict__ qkvh,
                                                 ushort* __restrict__ vth) {
    int bh = blockIdx.y;
    int b = bh >> 3, h = bh & 7;
    int kv0 = blockIdx.x * 32;
    __shared__ ushort smh[32][33];
    int tid = threadIdx.x;
    #pragma unroll
    for (int p = 0; p < 4; ++p) {
        int kv = p * 8 + (tid >> 5);
        int d = tid & 31;
        size_t src = ((size_t)(b * 1024 + kv0 + kv)) * 768 + 512 + h * 32 + d;
        smh[kv][d] = qkvh[src];
    }
    __syncthreads();
    #pragma unroll
    for (int p = 0; p < 4; ++p) {
        int d = p * 8 + (tid >> 5);
        int kv = tid & 31;
        size_t dst = ((size_t)(bh * 32 + d)) * 1024 + kv0 + kv;
        vth[dst] = smh[kv][d];
    }
}

// ---------------- MFMA flash attention v7: max-free, KVBLK=128 ----------------
__global__ __launch_bounds__(256, 4) void attention_mfma(const ushort* __restrict__ qkvh,
                                                         const ushort* __restrict__ vth,
                                                         ushort* __restrict__ ohi) {
    int b = blockIdx.z, h = blockIdx.y;
    int q0 = blockIdx.x * 64;
    int tid = threadIdx.x;
    int w = tid >> 6, l = tid & 63;
    int c = l & 15, g = l >> 4;
    __shared__ ushort Kh[128][40];
    __shared__ ushort VTh[32][136];
    __shared__ ushort Ph[4][16][140];

    size_t qbase = ((size_t)(b * 1024 + q0 + w * 16 + c)) * 768 + h * 32 + g * 8;
    short8 qa_h = *(const short8*)&qkvh[qbase];

    f32x4 acc_o[2] = {};
    float lpart[4] = {0.f, 0.f, 0.f, 0.f};
    const float scale = 0.17677669529663687f;

    int sr = tid >> 2, sc8 = (tid & 3) * 8;
    size_t kgbase = ((size_t)(b * 1024 + sr)) * 768 + 256 + h * 32 + sc8;
    int vd = tid >> 4, vk8 = (tid & 15) * 8;
    size_t vtbase = ((size_t)((b * 8 + h) * 32 + vd)) * 1024 + vk8;

    for (int kv0 = 0; kv0 < 1024; kv0 += 128) {
        __syncthreads();
        *(uint4*)&Kh[sr][sc8]       = *(const uint4*)&qkvh[kgbase + (size_t)kv0 * 768];
        *(uint4*)&Kh[sr + 64][sc8]  = *(const uint4*)&qkvh[kgbase + (size_t)(kv0 + 64) * 768];
        *(uint4*)&VTh[vd][vk8]      = *(const uint4*)&vth[vtbase + kv0];
        *(uint4*)&VTh[vd + 16][vk8] = *(const uint4*)&vth[vtbase + 16 * 1024 + kv0];
        __syncthreads();

        f32x4 s4[8];
        #pragma unroll
        for (int t = 0; t < 8; ++t) {
            short8 kh = *(const short8*)&Kh[t * 16 + c][g * 8];
            f32x4 a = {};
            a = __builtin_amdgcn_mfma_f32_16x16x32_bf16(qa_h, kh, a, 0, 0, 0);
            s4[t] = a;
        }

        #pragma unroll
        for (int rr = 0; rr < 4; ++rr) {
            float sum = 0.f;
            #pragma unroll
            for (int t = 0; t < 8; ++t) {
                float p = __expf(s4[t][rr] * scale);
                uint u = __float_as_uint(p);
                uint r = (u + 0x7FFFu + ((u >> 16) & 1u)) >> 16;
                Ph[w][g * 4 + rr][t * 16 + c] = (ushort)r;
                sum += __uint_as_float(r << 16);
            }
            lpart[rr] += sum;
        }
        asm volatile("s_waitcnt lgkmcnt(0)" ::: "memory");

        #pragma unroll
        for (int kt = 0; kt < 4; ++kt) {
            short8 pah = *(const short8*)&Ph[w][c][kt * 32 + g * 8];
            #pragma unroll
            for (int T = 0; T < 2; ++T) {
                short8 vh = *(const short8*)&VTh[T * 16 + c][kt * 32 + g * 8];
                acc_o[T] = __builtin_amdgcn_mfma_f32_16x16x32_bf16(pah, vh, acc_o[T], 0, 0, 0);
            }
        }
    }

    #pragma unroll
    for (int rr = 0; rr < 4; ++rr) {
        float s = lpart[rr];
        s += __shfl_xor(s, 1);
        s += __shfl_xor(s, 2);
        s += __shfl_xor(s, 4);
        s += __shfl_xor(s, 8);
        lpart[rr] = s;
    }

    #pragma unroll
    for (int rr = 0; rr < 4; ++rr) {
        float inv = 1.0f / lpart[rr];
        int q = q0 + w * 16 + g * 4 + rr;
        #pragma unroll
        for (int T = 0; T < 2; ++T) {
            float v = acc_o[T][rr] * inv;
            size_t idx = (size_t)(b * 1024 + q) * 256 + h * 32 + T * 16 + c;
            ohi[idx] = rnd_bf16(v);
        }
    }
}

// ---------------- MFMA FFN1 128x128 BK=64, XCD-swizzled 1D grid ----------------
__global__ __launch_bounds__(256) void mfma_ffn1_128128(const ushort* __restrict__ Ah,
                                                        const ushort* __restrict__ W1h,
                                                        const float* __restrict__ b1l,
                                                        ushort* __restrict__ hh,
                                                        const int* __restrict__ ib,
                                                        int c0, int hFF, int NC) {
    int tileIdx, cj;
    xcd_map(blockIdx.x, NC, tileIdx, cj);
    if (tileIdx >= ib[IB_NTILES]) return;
    int e = ib[IB_TILE_E + tileIdx];
    int row0 = ib[IB_TILE_R0 + tileIdx];
    int rowend = ib[IB_TILE_RE + tileIdx];
    __shared__ ushort LAh[128][64], LBh[128][64];
    __shared__ int tok[128];
    int tid = threadIdx.x;
    if (tid < 128) {
        int sr = row0 + tid;
        tok[tid] = ib[IB_STOK + (sr < rowend ? sr : row0)];
    }
    __syncthreads();
    int w = tid >> 6, l = tid & 63, c = l & 15, G = l >> 4;
    int lr = l >> 3, sd = l & 7;
    int colbase = cj * 128;
    const ushort* Bh = W1h + (size_t)e * 262144 + (size_t)(c0 + colbase) * 256;
    size_t gaA[4]; ushort* dA[4];
    size_t gbB[4]; ushort* dB[4];
    #pragma unroll
    for (int i = 0; i < 4; ++i) {
        int r = i * 32 + w * 8 + lr;
        gaA[i] = (size_t)tok[r] * 256 + ((sd ^ (r & 7)) << 3);
        dA[i] = &LAh[i * 32 + w * 8][0];
        gbB[i] = (size_t)r * 256 + ((sd ^ (r & 7)) << 3);
        dB[i] = &LBh[i * 32 + w * 8][0];
    }
    f32x4 acc[2][8] = {};
    for (int k0 = 0; k0 < 256; k0 += 64) {
        #pragma unroll
        for (int i = 0; i < 4; ++i) gld16(&Ah[gaA[i] + k0], dA[i]);
        #pragma unroll
        for (int i = 0; i < 4; ++i) gld16(&Bh[gbB[i] + k0], dB[i]);
        __syncthreads();
        #pragma unroll
        for (int s = 0; s < 2; ++s) {
            int ar = w * 32 + c;
            short8 a_h[2];
            #pragma unroll
            for (int i = 0; i < 2; ++i) {
                int r = ar + i * 16;
                int sg = (((s << 2) | G) ^ (r & 7)) << 3;
                a_h[i] = *(const short8*)&LAh[r][sg];
            }
            #pragma unroll
            for (int j = 0; j < 8; ++j) {
                int r = j * 16 + c;
                int sg = (((s << 2) | G) ^ (r & 7)) << 3;
                short8 b_h = *(const short8*)&LBh[r][sg];
                #pragma unroll
                for (int i = 0; i < 2; ++i) {
                    acc[i][j] = __builtin_amdgcn_mfma_f32_16x16x32_bf16(a_h[i], b_h, acc[i][j], 0, 0, 0);
                }
            }
        }
        __syncthreads();
    }
    int rbase = row0 + w * 32 + G * 4;
    #pragma unroll
    for (int i = 0; i < 2; ++i) {
        #pragma unroll
        for (int j = 0; j < 8; ++j) {
            int cl = colbase + j * 16 + c;
            float bv = b1l[(size_t)e * FFD + c0 + cl];
            #pragma unroll
            for (int rr = 0; rr < 4; ++rr) {
                int sr = rbase + i * 16 + rr;
                if (sr < rowend) {
                    float v = gelu_exact(acc[i][j][rr] + bv);
                    hh[(size_t)sr * hFF + cl] = rnd_bf16(v);
                }
            }
        }
    }
}

// ---------------- MFMA FFN2 128x128 BK=64, XCD-swizzled 1D grid ----------------
__global__ __launch_bounds__(256) void mfma_ffn2_128128(const ushort* __restrict__ Ah,
                                                        const ushort* __restrict__ W2h,
                                                        const float* __restrict__ b2l,
                                                        float* __restrict__ sout,
                                                        const int* __restrict__ ib,
                                                        int c0, int hFF, int NC) {
    int tileIdx, cj;
    xcd_map(blockIdx.x, NC, tileIdx, cj);
    if (tileIdx >= ib[IB_NTILES]) return;
    int e = ib[IB_TILE_E + tileIdx];
    int row0 = ib[IB_TILE_R0 + tileIdx];
    int rowend = ib[IB_TILE_RE + tileIdx];
    __shared__ ushort LAh[128][64], LBh[128][64];
    int tid = threadIdx.x;
    int w = tid >> 6, l = tid & 63, c = l & 15, G = l >> 4;
    int lr = l >> 3, sd = l & 7;
    int colbase = cj * 128;
    const ushort* Bh = W2h + (size_t)e * 262144;
    size_t gaA[4]; ushort* dA[4];
    size_t gbB[4]; ushort* dB[4];
    #pragma unroll
    for (int i = 0; i < 4; ++i) {
        int r = i * 32 + w * 8 + lr;
        gaA[i] = (size_t)(row0 + r) * hFF + ((sd ^ (r & 7)) << 3);
        dA[i] = &LAh[i * 32 + w * 8][0];
        gbB[i] = (size_t)(colbase + r) * 1024 + c0 + ((sd ^ (r & 7)) << 3);
        dB[i] = &LBh[i * 32 + w * 8][0];
    }
    f32x4 acc[2][8] = {};
    for (int k0 = 0; k0 < hFF; k0 += 64) {
        #pragma unroll
        for (int i = 0; i < 4; ++i) gld16(&Ah[gaA[i] + k0], dA[i]);
        #pragma unroll
        for (int i = 0; i < 4; ++i) gld16(&Bh[gbB[i] + k0], dB[i]);
        __syncthreads();
        #pragma unroll
        for (int s = 0; s < 2; ++s) {
            int ar = w * 32 + c;
            short8 a_h[2];
            #pragma unroll
            for (int i = 0; i < 2; ++i) {
                int r = ar + i * 16;
                int sg = (((s << 2) | G) ^ (r & 7)) << 3;
                a_h[i] = *(const short8*)&LAh[r][sg];
            }
            #pragma unroll
            for (int j = 0; j < 8; ++j) {
                int r = j * 16 + c;
                int sg = (((s << 2) | G) ^ (r & 7)) << 3;
                short8 b_h = *(const short8*)&LBh[r][sg];
                #pragma unroll
                for (int i = 0; i < 2; ++i) {
                    acc[i][j] = __builtin_amdgcn_mfma_f32_16x16x32_bf16(a_h[i], b_h, acc[i][j], 0, 0, 0);
                }
            }
        }
        __syncthreads();
    }
    int rbase = row0 + w * 32 + G * 4;
    #pragma unroll
    for (int i = 0; i < 2; ++i) {
        #pragma unroll
        for (int j = 0; j < 8; ++j) {
            int n = colbase + j * 16 + c;
            float bv = b2l[(size_t)e * DIM + n];
            #pragma unroll
            for (int rr = 0; rr < 4; ++rr) {
                int sr = rbase + i * 16 + rr;
                if (sr < rowend) {
                    size_t idx = (size_t)sr * 256 + n;
                    if (c0 == 0) sout[idx] = acc[i][j][rr] + bv;
                    else         sout[idx] += acc[i][j][rr];
                }
            }
        }
    }
}

// ---------------- gate + top2 v3: LDS histogram, NO global atomics ----------------
__global__ __launch_bounds__(256) void gate_topk(const float* __restrict__ lnb,
                                                 const float* __restrict__ gw,
                                                 const float* __restrict__ gb,
                                                 float* __restrict__ gv, int* __restrict__ ib) {
    __shared__ int hist[8];
    int tid = threadIdx.x;
    if (tid < 8) hist[tid] = 0;
    __syncthreads();
    int grp = tid >> 3, ln8 = tid & 7;
    int t = blockIdx.x * 32 + grp;
    const float* x = lnb + (size_t)t * DIM + ln8 * 32;
    const float* wb = gw + (size_t)ln8 * 32 * 8;
    float g[8] = {};
    #pragma unroll
    for (int d4 = 0; d4 < 8; ++d4) {
        float4 xv = *(const float4*)&x[d4 * 4];
        const float* wr = wb + d4 * 32;
        float4 wa0 = *(const float4*)&wr[0],  wb0 = *(const float4*)&wr[4];
        float4 wa1 = *(const float4*)&wr[8],  wb1 = *(const float4*)&wr[12];
        float4 wa2 = *(const float4*)&wr[16], wb2 = *(const float4*)&wr[20];
        float4 wa3 = *(const float4*)&wr[24], wb3 = *(const float4*)&wr[28];
        g[0] += xv.x * wa0.x + xv.y * wa1.x + xv.z * wa2.x + xv.w * wa3.x;
        g[1] += xv.x * wa0.y + xv.y * wa1.y + xv.z * wa2.y + xv.w * wa3.y;
        g[2] += xv.x * wa0.z + xv.y * wa1.z + xv.z * wa2.z + xv.w * wa3.z;
        g[3] += xv.x * wa0.w + xv.y * wa1.w + xv.z * wa2.w + xv.w * wa3.w;
        g[4] += xv.x * wb0.x + xv.y * wb1.x + xv.z * wb2.x + xv.w * wb3.x;
        g[5] += xv.x * wb0.y + xv.y * wb1.y + xv.z * wb2.y + xv.w * wb3.y;
        g[6] += xv.x * wb0.z + xv.y * wb1.z + xv.z * wb2.z + xv.w * wb3.z;
        g[7] += xv.x * wb0.w + xv.y * wb1.w + xv.z * wb2.w + xv.w * wb3.w;
    }
    #pragma unroll
    for (int e = 0; e < 8; ++e) {
        g[e] += __shfl_xor(g[e], 1);
        g[e] += __shfl_xor(g[e], 2);
        g[e] += __shfl_xor(g[e], 4);
    }
    if (ln8 == 0) {
        #pragma unroll
        for (int e = 0; e < 8; ++e) g[e] += gb[e];
        int i0 = 0; float s0 = g[0];
        #pragma unroll
        for (int e = 1; e < 8; ++e) if (g[e] > s0) { s0 = g[e]; i0 = e; }
        int i1 = -1; float s1 = -1e30f;
        #pragma unroll
        for (int e = 0; e < 8; ++e) if (e != i0 && g[e] > s1) { s1 = g[e]; i1 = e; }
        float e1 = __expf(s1 - s0);
        float w0v = 1.0f / (1.0f + e1);
        float w1v = e1 / (1.0f + e1);
        gv[2 * t] = w0v; gv[2 * t + 1] = w1v;
        ib[IB_GIDX + 2 * t] = i0; ib[IB_GIDX + 2 * t + 1] = i1;
        atomicAdd(&hist[i0], 1);
        atomicAdd(&hist[i1], 1);
    }
    __syncthreads();
    if (tid < 8) ib[IB_BLKC + blockIdx.x * 8 + tid] = hist[tid];
}

// ---------------- scan: totals, offsets, per-block bases, tile table ----------------
__global__ __launch_bounds__(256) void scan_tiles(int* ib) {
    __shared__ int bc[2048], bb[2048];
    __shared__ int counts[8], offs[8], tstart[9];
    int tid = threadIdx.x;
    for (int i = tid; i < 2048; i += 256) bc[i] = ib[IB_BLKC + i];
    __syncthreads();
    if (tid < 8) {
        int run = 0;
        for (int b = 0; b < 256; ++b) {
            bb[b * 8 + tid] = run;
            run += bc[b * 8 + tid];
        }
        counts[tid] = run;
    }
    __syncthreads();
    if (tid == 0) {
        int off = 0, ts = 0;
        for (int e = 0; e < 8; ++e) {
            offs[e] = off;
            ib[IB_OFFS + e] = off;
            tstart[e] = ts;
            ib[IB_COUNTS + e] = counts[e];
            ts += (counts[e] + 127) >> 7;
            off += counts[e];
        }
        tstart[8] = ts;
        ib[IB_NTILES] = ts;
    }
    __syncthreads();
    for (int i = tid; i < 2048; i += 256)
        ib[IB_BLKB + i] = offs[i & 7] + bb[i];
    int total = tstart[8];
    for (int idx = tid; idx < total; idx += 256) {
        int e = 0;
        while (idx >= tstart[e + 1]) ++e;
        int i = idx - tstart[e];
        ib[IB_TILE_E + idx] = e;
        ib[IB_TILE_R0 + idx] = offs[e] + i * 128;
        int rem = counts[e] - i * 128;
        ib[IB_TILE_RE + idx] = offs[e] + i * 128 + (rem < 128 ? rem : 128);
    }
}

// ---------------- scatter to slots ----------------
__global__ __launch_bounds__(64) void scatter_slots(int* ib) {
    __shared__ int cnt8[8];
    int tid = threadIdx.x;
    if (tid < 8) cnt8[tid] = ib[IB_BLKB + blockIdx.x * 8 + tid];
    __syncthreads();
    int t = blockIdx.x * 32 + (tid >> 1);
    int k = tid & 1;
    int e = ib[IB_GIDX + 2 * t + k];
    int pos = atomicAdd(&cnt8[e], 1);
    ib[IB_STOK + pos] = t;
    ib[IB_SPOS + 2 * t + k] = pos;
}

// ---------------- gather ----------------
__global__ __launch_bounds__(64) void moe_gather(float* __restrict__ xb,
                                                 const float* __restrict__ sout,
                                                 const float* __restrict__ gv,
                                                 const int* __restrict__ ib) {
    int t = blockIdx.x;
    int d = threadIdx.x * 4;
    int p0 = ib[IB_SPOS + 2 * t], p1 = ib[IB_SPOS + 2 * t + 1];
    float g0 = gv[2 * t], g1 = gv[2 * t + 1];
    float4 xv = *(float4*)&xb[(size_t)t * 256 + d];
    float4 s0 = *(const float4*)&sout[(size_t)p0 * 256 + d];
    float4 s1 = *(const float4*)&sout[(size_t)p1 * 256 + d];
    xv.x += g0 * s0.x + g1 * s1.x;
    xv.y += g0 * s0.y + g1 * s1.y;
    xv.z += g0 * s0.z + g1 * s1.z;
    xv.w += g0 * s0.w + g1 * s1.w;
    *(float4*)&xb[(size_t)t * 256 + d] = xv;
}

// ---------------- pooling ----------------
__global__ __launch_bounds__(256) void pool1(const float* __restrict__ xb, float* __restrict__ pp) {
    int b = blockIdx.x, ch = blockIdx.y, d = threadIdx.x;
    float s = 0.0f;
    for (int i = 0; i < 32; ++i) s += xb[((size_t)b * 1024 + ch * 32 + i) * 256 + d];
    pp[(size_t)(b * 32 + ch) * 256 + d] = s;
}
__global__ __launch_bounds__(256) void pool2(const float* __restrict__ pp, float* __restrict__ pool) {
    int b = blockIdx.x, d = threadIdx.x;
    float s = 0.0f;
    for (int c = 0; c < 32; ++c) s += pp[(size_t)(b * 32 + c) * 256 + d];
    pool[(size_t)b * 256 + d] = s * (1.0f / 1024.0f);
}

// ---------------- head ----------------
__global__ __launch_bounds__(256) void head_kernel(const float* __restrict__ pool,
                                                   const float* __restrict__ hw,
                                                   const float* __restrict__ hb,
                                                   float* __restrict__ out) {
    __shared__ float P[2048];
    int tid = threadIdx.x;
    for (int i = tid; i < 2048; i += 256) P[i] = pool[i];
    __syncthreads();
    int j = blockIdx.x * 256 + tid;
    if (j >= NOUT) return;
    float acc[8] = {};
    for (int d = 0; d < 256; ++d) {
        float w = hw[(size_t)d * NOUT + j];
        #pragma unroll
        for (int b = 0; b < 8; ++b) acc[b] += P[b * 256 + d] * w;
    }
    #pragma unroll
    for (int b = 0; b < 8; ++b) out[(size_t)b * NOUT + j] = acc[b] + hb[j];
}

extern "C" void kernel_launch(void* const* d_in, const int* in_sizes, int n_in,
                              void* d_out, int out_size, void* d_ws, size_t ws_size,
                              hipStream_t stream) {
    const float* x      = (const float*)d_in[0];
    const float* qkv_w  = (const float*)d_in[1];
    const float* qkv_b  = (const float*)d_in[2];
    const float* attn_w = (const float*)d_in[3];
    const float* attn_b = (const float*)d_in[4];
    const float* gate_w = (const float*)d_in[5];
    const float* gate_b = (const float*)d_in[6];
    const float* e_w1   = (const float*)d_in[7];
    const float* e_b1   = (const float*)d_in[8];
    const float* e_w2   = (const float*)d_in[9];
    const float* e_b2   = (const float*)d_in[10];
    const float* ln1_g  = (const float*)d_in[11];
    const float* ln1_b  = (const float*)d_in[12];
    const float* ln2_g  = (const float*)d_in[13];
    const float* ln2_b  = (const float*)d_in[14];
    const float* head_w = (const float*)d_in[15];
    const float* head_b = (const float*)d_in[16];
    float* out = (float*)d_out;
    float* wsf = (float*)d_ws;

    float* xb   = wsf + WS_X;
    float* lnb  = wsf + WS_LN;
    float* sob  = wsf + WS_SOUT;
    float* gv   = wsf + WS_GV;
    float* pp   = wsf + WS_PP;
    float* pool = wsf + WS_POOL;
    int*   ib   = (int*)(wsf + WS_INT);

    ushort* qkvsh = (ushort*)(wsf + WS_QKV);
    ushort* wT    = (ushort*)(wsf + WS_QKV);
    ushort* w1th  = wT;
    ushort* w2th  = wT + 4194304;
    ushort* wTdummy = wT + 6291456;

    ushort* vth = (ushort*)(wsf + WS_H);

    ushort* u16  = (ushort*)(wsf + WS_U16);
    ushort* lnh  = u16;
    ushort* qwh  = u16 + 4194304;
    ushort* awh  = u16 + 4587520;

    // ---- adaptive FFN chunking (h is bf16-only: NSLOT*hFF*2 bytes) ----
    size_t base_bytes = (size_t)WS_BIG * 4;
    int hFF = 256;
    if (ws_size >= base_bytes + (size_t)NSLOT * 1024 * 2)      hFF = 1024;
    else if (ws_size >= base_bytes + (size_t)NSLOT * 512 * 2)  hFF = 512;
    ushort* hh = (hFF == 256) ? (ushort*)(wsf + WS_H) : (ushort*)(wsf + WS_BIG);
    int NCC = 1024 / hFF;

    hipMemcpyAsync(xb, x, (size_t)TOK * DIM * sizeof(float), hipMemcpyDeviceToDevice, stream);

    for (int l = 0; l < NL; ++l) {
        // --- attention block ---
        ln_split<false><<<TOK / 4, 256, 0, stream>>>(xb, nullptr, lnh, ln1_g, ln1_b);
        split_transpose<false><<<dim3(8, 24, 1), 256, 0, stream>>>(
            qkv_w + (size_t)l * DIM * 3 * DIM, qwh, wTdummy, 256, 768);
        mfma_dense128x128<3><<<64 * 6, 256, 0, stream>>>(
            lnh, qwh, qkv_b + (size_t)l * 3 * DIM, nullptr, qkvsh, 768, 6);
        vt_kernel<<<dim3(32, 64), 256, 0, stream>>>(qkvsh, vth);
        attention_mfma<<<dim3(16, NH, 8), 256, 0, stream>>>(qkvsh, vth, lnh);
        split_transpose<false><<<dim3(8, 8, 1), 256, 0, stream>>>(
            attn_w + (size_t)l * DIM * DIM, awh, wTdummy, 256, 256);
        mfma_dense128x128<1><<<64 * 2, 256, 0, stream>>>(
            lnh, awh, attn_b + (size_t)l * DIM, xb, nullptr, 256, 2);

        // --- MoE block ---
        ln_split<true><<<TOK / 4, 256, 0, stream>>>(xb, lnb, lnh, ln2_g, ln2_b);
        split_transpose<false><<<dim3(8, 32, 8), 256, 0, stream>>>(
            e_w1 + (size_t)l * NE * DIM * FFD, w1th, wTdummy, 256, 1024);
        split_transpose<false><<<dim3(32, 8, 8), 256, 0, stream>>>(
            e_w2 + (size_t)l * NE * FFD * DIM, w2th, wTdummy, 1024, 256);
        gate_topk<<<TOK / 32, 256, 0, stream>>>(
            lnb, gate_w + (size_t)l * DIM * NE, gate_b + (size_t)l * NE, gv, ib);
        scan_tiles<<<1, 256, 0, stream>>>(ib);
        scatter_slots<<<TOK / 32, 64, 0, stream>>>(ib);
        for (int c = 0; c < NCC; ++c) {
            mfma_ffn1_128128<<<136 * (hFF / 128), 256, 0, stream>>>(
                lnh, w1th, e_b1 + (size_t)l * NE * FFD, hh, ib, c * hFF, hFF, hFF / 128);
            mfma_ffn2_128128<<<136 * 2, 256, 0, stream>>>(
                hh, w2th, e_b2 + (size_t)l * NE * DIM, sob, ib, c * hFF, hFF, 2);
        }
        moe_gather<<<TOK, 64, 0, stream>>>(xb, sob, gv, ib);
    }

    pool1<<<dim3(8, 32), 256, 0, stream>>>(xb, pp);
    pool2<<<8, 256, 0, stream>>>(pp, pool);
    head_kernel<<<4, 256, 0, stream>>>(pool, head_w, head_b, out);
}

// Round 30
// 333.984 us; speedup vs baseline: 1.1754x; 1.1754x over previous
//
#include <hip/hip_runtime.h>
#include <math.h>

#define TOK   8192
#define DIM   256
#define NH    8
#define HDIM  32
#define FFD   1024
#define NE    8
#define NL    2
#define NOUT  1000
#define NSLOT 16384   // TOK*2

typedef unsigned int uint;
typedef unsigned short ushort;
typedef __attribute__((ext_vector_type(8))) short short8;
typedef __attribute__((ext_vector_type(4))) float f32x4;

// ---------------- workspace layout (float units) ----------------
#define WS_X     ((size_t)0)
#define WS_LN    (WS_X    + (size_t)TOK*DIM)
#define WS_QKV   (WS_LN   + (size_t)TOK*DIM)
#define WS_H     (WS_QKV  + (size_t)TOK*3*DIM)
#define WS_SOUT  (WS_H    + (size_t)NSLOT*256)
#define WS_GV    (WS_SOUT + (size_t)NSLOT*256)
#define WS_PP    (WS_GV   + (size_t)TOK*2)
#define WS_POOL  (WS_PP   + (size_t)8*32*256)
#define WS_INT   (WS_POOL + (size_t)8*256)
#define WS_U16   (WS_INT  + (size_t)54144)
#define WS_BIG   (WS_U16  + (size_t)2359296)

// int region layout (int32 indices)
#define IB_COUNTS   0
#define IB_NTILES   8
#define IB_OFFS     16
#define IB_CURS     24
#define IB_TILE_E   32
#define IB_TILE_R0  320
#define IB_TILE_RE  608
#define IB_GIDX     896    // [TOK*2]
#define IB_SPOS     17280  // [TOK*2]
#define IB_STOK     33664  // [NSLOT]
#define IB_BLKC     50048  // [256*8]
#define IB_BLKB     52096  // [256*8]

// fast erf (Abramowitz-Stegun 7.1.26, |err| <= 1.5e-7) — error far below the
// bf16 rounding (2e-3 rel) applied to h right after.
__device__ __forceinline__ float gelu_exact(float v) {
    float z = v * 0.70710678118654752f;
    float s = fabsf(z);
    float t = __builtin_amdgcn_rcpf(1.0f + 0.3275911f * s);
    float p = ((((1.061405429f * t - 1.453152027f) * t + 1.421413741f) * t
                - 0.284496736f) * t + 0.254829592f) * t;
    float r = 1.0f - p * __expf(-s * s);
    float er = (z < 0.0f) ? -r : r;
    return 0.5f * v * (1.0f + er);
}

__device__ __forceinline__ ushort rnd_bf16(float x) {
    uint u = __float_as_uint(x);
    return (ushort)((u + 0x7FFFu + ((u >> 16) & 1u)) >> 16);
}

__device__ __forceinline__ void split2(float x, ushort& h, ushort& lo) {
    uint u = __float_as_uint(x);
    uint hh = (u + 0x7FFFu + ((u >> 16) & 1u)) >> 16;
    h = (ushort)hh;
    float hf = __uint_as_float(hh << 16);
    float l = x - hf;
    uint ul = __float_as_uint(l);
    lo = (ushort)((ul + 0x7FFFu + ((ul >> 16) & 1u)) >> 16);
}

// async global->LDS 16B: dest = wave-uniform base + lane*16 (linear); source per-lane.
__device__ __forceinline__ void gld16(const ushort* g, ushort* l) {
    __builtin_amdgcn_global_load_lds(
        (const __attribute__((address_space(1))) uint*)g,
        (__attribute__((address_space(3))) uint*)l, 16, 0, 0);
}

// XCD-aware decode: all NC col-blocks of a tile share bid%8 -> same XCD L2.
// Bijective for NT % 8 == 0. HW round-robins XCD by hardware block id.
__device__ __forceinline__ void xcd_map(int bid, int NC, int& t, int& j) {
    int g = bid >> 3;
    t = (bid & 7) + 8 * (g / NC);
    j = g % NC;
}

// ---------------- LayerNorm -> bf16 (hi-only) output (+optional f32) ----------------
template<bool WF32>
__global__ __launch_bounds__(256) void ln_split(const float* __restrict__ x,
                                                float* __restrict__ out,
                                                ushort* __restrict__ ohi,
                                                const float* __restrict__ g,
                                                const float* __restrict__ b) {
    int wave = threadIdx.x >> 6;
    int lane = threadIdx.x & 63;
    int t = blockIdx.x * 4 + wave;
    const float* xp = x + (size_t)t * DIM;
    float4 v = *(const float4*)&xp[lane * 4];
    float s = v.x + v.y + v.z + v.w;
    #pragma unroll
    for (int off = 32; off; off >>= 1) s += __shfl_xor(s, off);
    float mean = s * (1.0f / 256.0f);
    float dx = v.x - mean, dy = v.y - mean, dz = v.z - mean, dw = v.w - mean;
    float vs = dx * dx + dy * dy + dz * dz + dw * dw;
    #pragma unroll
    for (int off = 32; off; off >>= 1) vs += __shfl_xor(vs, off);
    float inv = rsqrtf(vs * (1.0f / 256.0f) + 1e-5f);
    float4 gg = *(const float4*)&g[lane * 4];
    float4 bb = *(const float4*)&b[lane * 4];
    float o0 = dx * inv * gg.x + bb.x;
    float o1 = dy * inv * gg.y + bb.y;
    float o2 = dz * inv * gg.z + bb.z;
    float o3 = dw * inv * gg.w + bb.w;
    size_t idx = (size_t)t * DIM + lane * 4;
    if (WF32) {
        float4 o; o.x = o0; o.y = o1; o.z = o2; o.w = o3;
        *(float4*)&out[idx] = o;
    }
    uint2 ph;
    ph.x = (uint)rnd_bf16(o0) | ((uint)rnd_bf16(o1) << 16);
    ph.y = (uint)rnd_bf16(o2) | ((uint)rnd_bf16(o3) << 16);
    *(uint2*)&ohi[idx] = ph;
}

// ---------------- split+transpose weights (WLO=false: hi only) ----------------
template<bool WLO>
__global__ __launch_bounds__(256) void split_transpose(const float* __restrict__ src,
                                                       ushort* __restrict__ dhi,
                                                       ushort* __restrict__ dlo,
                                                       int K, int N) {
    int z = blockIdx.z;
    const float* s = src + (size_t)z * K * N;
    ushort* th = dhi + (size_t)z * K * N;
    ushort* tl = dlo + (size_t)z * K * N;
    __shared__ float tile[32][33];
    int k0 = blockIdx.x * 32, n0 = blockIdx.y * 32;
    int tx = threadIdx.x & 31, ty = threadIdx.x >> 5;
    #pragma unroll
    for (int i = 0; i < 4; ++i) {
        int k = k0 + ty + i * 8;
        tile[ty + i * 8][tx] = s[(size_t)k * N + n0 + tx];
    }
    __syncthreads();
    #pragma unroll
    for (int i = 0; i < 4; ++i) {
        int n = n0 + ty + i * 8;
        float v = tile[tx][ty + i * 8];
        ushort h, lo;
        split2(v, h, lo);
        th[(size_t)n * K + k0 + tx] = h;
        if (WLO) tl[(size_t)n * K + k0 + tx] = lo;
    }
}

// ============ 128x64 GEMM core, BK=64, all hi-only, XCD-swizzled 1D grid ============
// MODE 0=f32 out, 1=f32+residual, 3=bf16 out. Grid = NT*NC blocks, NT%8==0.

template<int MODE>
__global__ __launch_bounds__(256) void mfma_dense128x64(const ushort* __restrict__ Ah,
                                                        const ushort* __restrict__ Bh,
                                                        const float* __restrict__ bias,
                                                        float* __restrict__ C,
                                                        ushort* __restrict__ Chi, int N, int NC) {
    __shared__ ushort LAh[128][64], LBh[64][64];
    int tT, tJ;
    xcd_map(blockIdx.x, NC, tT, tJ);
    int tid = threadIdx.x;
    int w = tid >> 6, l = tid & 63, c = l & 15, G = l >> 4;
    int row0 = tT * 128, col0 = tJ * 64;
    int lr = l >> 3, sd = l & 7;
    size_t gaA[4]; ushort* dA[4];
    size_t gbB[2]; ushort* dB[2];
    #pragma unroll
    for (int i = 0; i < 4; ++i) {
        int r = i * 32 + w * 8 + lr;
        gaA[i] = (size_t)(row0 + r) * 256 + ((sd ^ (r & 7)) << 3);
        dA[i] = &LAh[i * 32 + w * 8][0];
    }
    #pragma unroll
    for (int i = 0; i < 2; ++i) {
        int r = i * 32 + w * 8 + lr;
        gbB[i] = (size_t)(col0 + r) * 256 + ((sd ^ (r & 7)) << 3);
        dB[i] = &LBh[i * 32 + w * 8][0];
    }
    f32x4 acc[2][4] = {};
    for (int k0 = 0; k0 < 256; k0 += 64) {
        #pragma unroll
        for (int i = 0; i < 4; ++i) gld16(&Ah[gaA[i] + k0], dA[i]);
        #pragma unroll
        for (int i = 0; i < 2; ++i) gld16(&Bh[gbB[i] + k0], dB[i]);
        __syncthreads();
        #pragma unroll
        for (int s = 0; s < 2; ++s) {
            int ar = w * 32 + c;
            short8 a_h[2];
            #pragma unroll
            for (int i = 0; i < 2; ++i) {
                int r = ar + i * 16;
                int sg = (((s << 2) | G) ^ (r & 7)) << 3;
                a_h[i] = *(const short8*)&LAh[r][sg];
            }
            #pragma unroll
            for (int j = 0; j < 4; ++j) {
                int r = j * 16 + c;
                int sg = (((s << 2) | G) ^ (r & 7)) << 3;
                short8 b_h = *(const short8*)&LBh[r][sg];
                #pragma unroll
                for (int i = 0; i < 2; ++i) {
                    acc[i][j] = __builtin_amdgcn_mfma_f32_16x16x32_bf16(a_h[i], b_h, acc[i][j], 0, 0, 0);
                }
            }
        }
        __syncthreads();
    }
    int rbase = row0 + w * 32 + G * 4;
    #pragma unroll
    for (int i = 0; i < 2; ++i) {
        #pragma unroll
        for (int j = 0; j < 4; ++j) {
            int gc = col0 + j * 16 + c;
            float bv = bias[gc];
            #pragma unroll
            for (int rr = 0; rr < 4; ++rr) {
                int grow = rbase + i * 16 + rr;
                size_t idx = (size_t)grow * N + gc;
                float v = acc[i][j][rr] + bv;
                if (MODE == 1) v += C[idx];
                if (MODE == 3) {
                    Chi[idx] = rnd_bf16(v);
                } else {
                    C[idx] = v;
                }
            }
        }
    }
}

// ---------------- V transpose (hi-only) ----------------
__global__ __launch_bounds__(256) void vt_kernel(const ushort* __restrict__ qkvh,
                                                 ushort* __restrict__ vth) {
    int bh = blockIdx.y;
    int b = bh >> 3, h = bh & 7;
    int kv0 = blockIdx.x * 32;
    __shared__ ushort smh[32][33];
    int tid = threadIdx.x;
    #pragma unroll
    for (int p = 0; p < 4; ++p) {
        int kv = p * 8 + (tid >> 5);
        int d = tid & 31;
        size_t src = ((size_t)(b * 1024 + kv0 + kv)) * 768 + 512 + h * 32 + d;
        smh[kv][d] = qkvh[src];
    }
    __syncthreads();
    #pragma unroll
    for (int p = 0; p < 4; ++p) {
        int d = p * 8 + (tid >> 5);
        int kv = tid & 31;
        size_t dst = ((size_t)(bh * 32 + d)) * 1024 + kv0 + kv;
        vth[dst] = smh[kv][d];
    }
}

// ---------------- MFMA flash attention v7: max-free, KVBLK=128 ----------------
__global__ __launch_bounds__(256, 4) void attention_mfma(const ushort* __restrict__ qkvh,
                                                         const ushort* __restrict__ vth,
                                                         ushort* __restrict__ ohi) {
    int b = blockIdx.z, h = blockIdx.y;
    int q0 = blockIdx.x * 64;
    int tid = threadIdx.x;
    int w = tid >> 6, l = tid & 63;
    int c = l & 15, g = l >> 4;
    __shared__ ushort Kh[128][40];
    __shared__ ushort VTh[32][136];
    __shared__ ushort Ph[4][16][140];

    size_t qbase = ((size_t)(b * 1024 + q0 + w * 16 + c)) * 768 + h * 32 + g * 8;
    short8 qa_h = *(const short8*)&qkvh[qbase];

    f32x4 acc_o[2] = {};
    float lpart[4] = {0.f, 0.f, 0.f, 0.f};
    const float scale = 0.17677669529663687f;

    int sr = tid >> 2, sc8 = (tid & 3) * 8;
    size_t kgbase = ((size_t)(b * 1024 + sr)) * 768 + 256 + h * 32 + sc8;
    int vd = tid >> 4, vk8 = (tid & 15) * 8;
    size_t vtbase = ((size_t)((b * 8 + h) * 32 + vd)) * 1024 + vk8;

    for (int kv0 = 0; kv0 < 1024; kv0 += 128) {
        __syncthreads();
        *(uint4*)&Kh[sr][sc8]       = *(const uint4*)&qkvh[kgbase + (size_t)kv0 * 768];
        *(uint4*)&Kh[sr + 64][sc8]  = *(const uint4*)&qkvh[kgbase + (size_t)(kv0 + 64) * 768];
        *(uint4*)&VTh[vd][vk8]      = *(const uint4*)&vth[vtbase + kv0];
        *(uint4*)&VTh[vd + 16][vk8] = *(const uint4*)&vth[vtbase + 16 * 1024 + kv0];
        __syncthreads();

        f32x4 s4[8];
        #pragma unroll
        for (int t = 0; t < 8; ++t) {
            short8 kh = *(const short8*)&Kh[t * 16 + c][g * 8];
            f32x4 a = {};
            a = __builtin_amdgcn_mfma_f32_16x16x32_bf16(qa_h, kh, a, 0, 0, 0);
            s4[t] = a;
        }

        #pragma unroll
        for (int rr = 0; rr < 4; ++rr) {
            float sum = 0.f;
            #pragma unroll
            for (int t = 0; t < 8; ++t) {
                float p = __expf(s4[t][rr] * scale);
                uint u = __float_as_uint(p);
                uint r = (u + 0x7FFFu + ((u >> 16) & 1u)) >> 16;
                Ph[w][g * 4 + rr][t * 16 + c] = (ushort)r;
                sum += __uint_as_float(r << 16);
            }
            lpart[rr] += sum;
        }
        asm volatile("s_waitcnt lgkmcnt(0)" ::: "memory");

        #pragma unroll
        for (int kt = 0; kt < 4; ++kt) {
            short8 pah = *(const short8*)&Ph[w][c][kt * 32 + g * 8];
            #pragma unroll
            for (int T = 0; T < 2; ++T) {
                short8 vh = *(const short8*)&VTh[T * 16 + c][kt * 32 + g * 8];
                acc_o[T] = __builtin_amdgcn_mfma_f32_16x16x32_bf16(pah, vh, acc_o[T], 0, 0, 0);
            }
        }
    }

    #pragma unroll
    for (int rr = 0; rr < 4; ++rr) {
        float s = lpart[rr];
        s += __shfl_xor(s, 1);
        s += __shfl_xor(s, 2);
        s += __shfl_xor(s, 4);
        s += __shfl_xor(s, 8);
        lpart[rr] = s;
    }

    #pragma unroll
    for (int rr = 0; rr < 4; ++rr) {
        float inv = 1.0f / lpart[rr];
        int q = q0 + w * 16 + g * 4 + rr;
        #pragma unroll
        for (int T = 0; T < 2; ++T) {
            float v = acc_o[T][rr] * inv;
            size_t idx = (size_t)(b * 1024 + q) * 256 + h * 32 + T * 16 + c;
            ohi[idx] = rnd_bf16(v);
        }
    }
}

// ---------------- MFMA FFN1 128x64 BK=64, XCD-swizzled 1D grid ----------------
__global__ __launch_bounds__(256) void mfma_ffn1_12864(const ushort* __restrict__ Ah,
                                                       const ushort* __restrict__ W1h,
                                                       const float* __restrict__ b1l,
                                                       ushort* __restrict__ hh,
                                                       const int* __restrict__ ib,
                                                       int c0, int hFF, int NC) {
    int tileIdx, cj;
    xcd_map(blockIdx.x, NC, tileIdx, cj);
    if (tileIdx >= ib[IB_NTILES]) return;
    int e = ib[IB_TILE_E + tileIdx];
    int row0 = ib[IB_TILE_R0 + tileIdx];
    int rowend = ib[IB_TILE_RE + tileIdx];
    __shared__ ushort LAh[128][64], LBh[64][64];
    __shared__ int tok[128];
    int tid = threadIdx.x;
    if (tid < 128) {
        int sr = row0 + tid;
        tok[tid] = ib[IB_STOK + (sr < rowend ? sr : row0)];
    }
    __syncthreads();
    int w = tid >> 6, l = tid & 63, c = l & 15, G = l >> 4;
    int lr = l >> 3, sd = l & 7;
    int colbase = cj * 64;
    const ushort* Bh = W1h + (size_t)e * 262144 + (size_t)(c0 + colbase) * 256;
    size_t gaA[4]; ushort* dA[4];
    size_t gbB[2]; ushort* dB[2];
    #pragma unroll
    for (int i = 0; i < 4; ++i) {
        int r = i * 32 + w * 8 + lr;
        gaA[i] = (size_t)tok[r] * 256 + ((sd ^ (r & 7)) << 3);
        dA[i] = &LAh[i * 32 + w * 8][0];
    }
    #pragma unroll
    for (int i = 0; i < 2; ++i) {
        int r = i * 32 + w * 8 + lr;
        gbB[i] = (size_t)r * 256 + ((sd ^ (r & 7)) << 3);
        dB[i] = &LBh[i * 32 + w * 8][0];
    }
    f32x4 acc[2][4] = {};
    for (int k0 = 0; k0 < 256; k0 += 64) {
        #pragma unroll
        for (int i = 0; i < 4; ++i) gld16(&Ah[gaA[i] + k0], dA[i]);
        #pragma unroll
        for (int i = 0; i < 2; ++i) gld16(&Bh[gbB[i] + k0], dB[i]);
        __syncthreads();
        #pragma unroll
        for (int s = 0; s < 2; ++s) {
            int ar = w * 32 + c;
            short8 a_h[2];
            #pragma unroll
            for (int i = 0; i < 2; ++i) {
                int r = ar + i * 16;
                int sg = (((s << 2) | G) ^ (r & 7)) << 3;
                a_h[i] = *(const short8*)&LAh[r][sg];
            }
            #pragma unroll
            for (int j = 0; j < 4; ++j) {
                int r = j * 16 + c;
                int sg = (((s << 2) | G) ^ (r & 7)) << 3;
                short8 b_h = *(const short8*)&LBh[r][sg];
                #pragma unroll
                for (int i = 0; i < 2; ++i) {
                    acc[i][j] = __builtin_amdgcn_mfma_f32_16x16x32_bf16(a_h[i], b_h, acc[i][j], 0, 0, 0);
                }
            }
        }
        __syncthreads();
    }
    int rbase = row0 + w * 32 + G * 4;
    #pragma unroll
    for (int i = 0; i < 2; ++i) {
        #pragma unroll
        for (int j = 0; j < 4; ++j) {
            int cl = colbase + j * 16 + c;
            float bv = b1l[(size_t)e * FFD + c0 + cl];
            #pragma unroll
            for (int rr = 0; rr < 4; ++rr) {
                int sr = rbase + i * 16 + rr;
                if (sr < rowend) {
                    float v = gelu_exact(acc[i][j][rr] + bv);
                    hh[(size_t)sr * hFF + cl] = rnd_bf16(v);
                }
            }
        }
    }
}

// ---------------- MFMA FFN2 128x64 BK=64, XCD-swizzled 1D grid ----------------
__global__ __launch_bounds__(256) void mfma_ffn2_12864(const ushort* __restrict__ Ah,
                                                       const ushort* __restrict__ W2h,
                                                       const float* __restrict__ b2l,
                                                       float* __restrict__ sout,
                                                       const int* __restrict__ ib,
                                                       int c0, int hFF, int NC) {
    int tileIdx, cj;
    xcd_map(blockIdx.x, NC, tileIdx, cj);
    if (tileIdx >= ib[IB_NTILES]) return;
    int e = ib[IB_TILE_E + tileIdx];
    int row0 = ib[IB_TILE_R0 + tileIdx];
    int rowend = ib[IB_TILE_RE + tileIdx];
    __shared__ ushort LAh[128][64], LBh[64][64];
    int tid = threadIdx.x;
    int w = tid >> 6, l = tid & 63, c = l & 15, G = l >> 4;
    int lr = l >> 3, sd = l & 7;
    int colbase = cj * 64;
    const ushort* Bh = W2h + (size_t)e * 262144;
    size_t gaA[4]; ushort* dA[4];
    size_t gbB[2]; ushort* dB[2];
    #pragma unroll
    for (int i = 0; i < 4; ++i) {
        int r = i * 32 + w * 8 + lr;
        gaA[i] = (size_t)(row0 + r) * hFF + ((sd ^ (r & 7)) << 3);
        dA[i] = &LAh[i * 32 + w * 8][0];
    }
    #pragma unroll
    for (int i = 0; i < 2; ++i) {
        int r = i * 32 + w * 8 + lr;
        gbB[i] = (size_t)(colbase + r) * 1024 + c0 + ((sd ^ (r & 7)) << 3);
        dB[i] = &LBh[i * 32 + w * 8][0];
    }
    f32x4 acc[2][4] = {};
    for (int k0 = 0; k0 < hFF; k0 += 64) {
        #pragma unroll
        for (int i = 0; i < 4; ++i) gld16(&Ah[gaA[i] + k0], dA[i]);
        #pragma unroll
        for (int i = 0; i < 2; ++i) gld16(&Bh[gbB[i] + k0], dB[i]);
        __syncthreads();
        #pragma unroll
        for (int s = 0; s < 2; ++s) {
            int ar = w * 32 + c;
            short8 a_h[2];
            #pragma unroll
            for (int i = 0; i < 2; ++i) {
                int r = ar + i * 16;
                int sg = (((s << 2) | G) ^ (r & 7)) << 3;
                a_h[i] = *(const short8*)&LAh[r][sg];
            }
            #pragma unroll
            for (int j = 0; j < 4; ++j) {
                int r = j * 16 + c;
                int sg = (((s << 2) | G) ^ (r & 7)) << 3;
                short8 b_h = *(const short8*)&LBh[r][sg];
                #pragma unroll
                for (int i = 0; i < 2; ++i) {
                    acc[i][j] = __builtin_amdgcn_mfma_f32_16x16x32_bf16(a_h[i], b_h, acc[i][j], 0, 0, 0);
                }
            }
        }
        __syncthreads();
    }
    int rbase = row0 + w * 32 + G * 4;
    #pragma unroll
    for (int i = 0; i < 2; ++i) {
        #pragma unroll
        for (int j = 0; j < 4; ++j) {
            int n = colbase + j * 16 + c;
            float bv = b2l[(size_t)e * DIM + n];
            #pragma unroll
            for (int rr = 0; rr < 4; ++rr) {
                int sr = rbase + i * 16 + rr;
                if (sr < rowend) {
                    size_t idx = (size_t)sr * 256 + n;
                    if (c0 == 0) sout[idx] = acc[i][j][rr] + bv;
                    else         sout[idx] += acc[i][j][rr];
                }
            }
        }
    }
}

// ---------------- gate + top2 v3: LDS histogram, NO global atomics ----------------
__global__ __launch_bounds__(256) void gate_topk(const float* __restrict__ lnb,
                                                 const float* __restrict__ gw,
                                                 const float* __restrict__ gb,
                                                 float* __restrict__ gv, int* __restrict__ ib) {
    __shared__ int hist[8];
    int tid = threadIdx.x;
    if (tid < 8) hist[tid] = 0;
    __syncthreads();
    int grp = tid >> 3, ln8 = tid & 7;
    int t = blockIdx.x * 32 + grp;
    const float* x = lnb + (size_t)t * DIM + ln8 * 32;
    const float* wb = gw + (size_t)ln8 * 32 * 8;
    float g[8] = {};
    #pragma unroll
    for (int d4 = 0; d4 < 8; ++d4) {
        float4 xv = *(const float4*)&x[d4 * 4];
        const float* wr = wb + d4 * 32;
        float4 wa0 = *(const float4*)&wr[0],  wb0 = *(const float4*)&wr[4];
        float4 wa1 = *(const float4*)&wr[8],  wb1 = *(const float4*)&wr[12];
        float4 wa2 = *(const float4*)&wr[16], wb2 = *(const float4*)&wr[20];
        float4 wa3 = *(const float4*)&wr[24], wb3 = *(const float4*)&wr[28];
        g[0] += xv.x * wa0.x + xv.y * wa1.x + xv.z * wa2.x + xv.w * wa3.x;
        g[1] += xv.x * wa0.y + xv.y * wa1.y + xv.z * wa2.y + xv.w * wa3.y;
        g[2] += xv.x * wa0.z + xv.y * wa1.z + xv.z * wa2.z + xv.w * wa3.z;
        g[3] += xv.x * wa0.w + xv.y * wa1.w + xv.z * wa2.w + xv.w * wa3.w;
        g[4] += xv.x * wb0.x + xv.y * wb1.x + xv.z * wb2.x + xv.w * wb3.x;
        g[5] += xv.x * wb0.y + xv.y * wb1.y + xv.z * wb2.y + xv.w * wb3.y;
        g[6] += xv.x * wb0.z + xv.y * wb1.z + xv.z * wb2.z + xv.w * wb3.z;
        g[7] += xv.x * wb0.w + xv.y * wb1.w + xv.z * wb2.w + xv.w * wb3.w;
    }
    #pragma unroll
    for (int e = 0; e < 8; ++e) {
        g[e] += __shfl_xor(g[e], 1);
        g[e] += __shfl_xor(g[e], 2);
        g[e] += __shfl_xor(g[e], 4);
    }
    if (ln8 == 0) {
        #pragma unroll
        for (int e = 0; e < 8; ++e) g[e] += gb[e];
        int i0 = 0; float s0 = g[0];
        #pragma unroll
        for (int e = 1; e < 8; ++e) if (g[e] > s0) { s0 = g[e]; i0 = e; }
        int i1 = -1; float s1 = -1e30f;
        #pragma unroll
        for (int e = 0; e < 8; ++e) if (e != i0 && g[e] > s1) { s1 = g[e]; i1 = e; }
        float e1 = __expf(s1 - s0);
        float w0v = 1.0f / (1.0f + e1);
        float w1v = e1 / (1.0f + e1);
        gv[2 * t] = w0v; gv[2 * t + 1] = w1v;
        ib[IB_GIDX + 2 * t] = i0; ib[IB_GIDX + 2 * t + 1] = i1;
        atomicAdd(&hist[i0], 1);
        atomicAdd(&hist[i1], 1);
    }
    __syncthreads();
    if (tid < 8) ib[IB_BLKC + blockIdx.x * 8 + tid] = hist[tid];
}

// ---------------- scan: totals, offsets, per-block bases, tile table ----------------
__global__ __launch_bounds__(256) void scan_tiles(int* ib) {
    __shared__ int bc[2048], bb[2048];
    __shared__ int counts[8], offs[8], tstart[9];
    int tid = threadIdx.x;
    for (int i = tid; i < 2048; i += 256) bc[i] = ib[IB_BLKC + i];
    __syncthreads();
    if (tid < 8) {
        int run = 0;
        for (int b = 0; b < 256; ++b) {
            bb[b * 8 + tid] = run;
            run += bc[b * 8 + tid];
        }
        counts[tid] = run;
    }
    __syncthreads();
    if (tid == 0) {
        int off = 0, ts = 0;
        for (int e = 0; e < 8; ++e) {
            offs[e] = off;
            ib[IB_OFFS + e] = off;
            tstart[e] = ts;
            ib[IB_COUNTS + e] = counts[e];
            ts += (counts[e] + 127) >> 7;
            off += counts[e];
        }
        tstart[8] = ts;
        ib[IB_NTILES] = ts;
    }
    __syncthreads();
    for (int i = tid; i < 2048; i += 256)
        ib[IB_BLKB + i] = offs[i & 7] + bb[i];
    int total = tstart[8];
    for (int idx = tid; idx < total; idx += 256) {
        int e = 0;
        while (idx >= tstart[e + 1]) ++e;
        int i = idx - tstart[e];
        ib[IB_TILE_E + idx] = e;
        ib[IB_TILE_R0 + idx] = offs[e] + i * 128;
        int rem = counts[e] - i * 128;
        ib[IB_TILE_RE + idx] = offs[e] + i * 128 + (rem < 128 ? rem : 128);
    }
}

// ---------------- scatter to slots ----------------
__global__ __launch_bounds__(64) void scatter_slots(int* ib) {
    __shared__ int cnt8[8];
    int tid = threadIdx.x;
    if (tid < 8) cnt8[tid] = ib[IB_BLKB + blockIdx.x * 8 + tid];
    __syncthreads();
    int t = blockIdx.x * 32 + (tid >> 1);
    int k = tid & 1;
    int e = ib[IB_GIDX + 2 * t + k];
    int pos = atomicAdd(&cnt8[e], 1);
    ib[IB_STOK + pos] = t;
    ib[IB_SPOS + 2 * t + k] = pos;
}

// ---------------- gather ----------------
__global__ __launch_bounds__(64) void moe_gather(float* __restrict__ xb,
                                                 const float* __restrict__ sout,
                                                 const float* __restrict__ gv,
                                                 const int* __restrict__ ib) {
    int t = blockIdx.x;
    int d = threadIdx.x * 4;
    int p0 = ib[IB_SPOS + 2 * t], p1 = ib[IB_SPOS + 2 * t + 1];
    float g0 = gv[2 * t], g1 = gv[2 * t + 1];
    float4 xv = *(float4*)&xb[(size_t)t * 256 + d];
    float4 s0 = *(const float4*)&sout[(size_t)p0 * 256 + d];
    float4 s1 = *(const float4*)&sout[(size_t)p1 * 256 + d];
    xv.x += g0 * s0.x + g1 * s1.x;
    xv.y += g0 * s0.y + g1 * s1.y;
    xv.z += g0 * s0.z + g1 * s1.z;
    xv.w += g0 * s0.w + g1 * s1.w;
    *(float4*)&xb[(size_t)t * 256 + d] = xv;
}

// ---------------- pooling ----------------
__global__ __launch_bounds__(256) void pool1(const float* __restrict__ xb, float* __restrict__ pp) {
    int b = blockIdx.x, ch = blockIdx.y, d = threadIdx.x;
    float s = 0.0f;
    for (int i = 0; i < 32; ++i) s += xb[((size_t)b * 1024 + ch * 32 + i) * 256 + d];
    pp[(size_t)(b * 32 + ch) * 256 + d] = s;
}
__global__ __launch_bounds__(256) void pool2(const float* __restrict__ pp, float* __restrict__ pool) {
    int b = blockIdx.x, d = threadIdx.x;
    float s = 0.0f;
    for (int c = 0; c < 32; ++c) s += pp[(size_t)(b * 32 + c) * 256 + d];
    pool[(size_t)b * 256 + d] = s * (1.0f / 1024.0f);
}

// ---------------- head ----------------
__global__ __launch_bounds__(256) void head_kernel(const float* __restrict__ pool,
                                                   const float* __restrict__ hw,
                                                   const float* __restrict__ hb,
                                                   float* __restrict__ out) {
    __shared__ float P[2048];
    int tid = threadIdx.x;
    for (int i = tid; i < 2048; i += 256) P[i] = pool[i];
    __syncthreads();
    int j = blockIdx.x * 256 + tid;
    if (j >= NOUT) return;
    float acc[8] = {};
    for (int d = 0; d < 256; ++d) {
        float w = hw[(size_t)d * NOUT + j];
        #pragma unroll
        for (int b = 0; b < 8; ++b) acc[b] += P[b * 256 + d] * w;
    }
    #pragma unroll
    for (int b = 0; b < 8; ++b) out[(size_t)b * NOUT + j] = acc[b] + hb[j];
}

extern "C" void kernel_launch(void* const* d_in, const int* in_sizes, int n_in,
                              void* d_out, int out_size, void* d_ws, size_t ws_size,
                              hipStream_t stream) {
    const float* x      = (const float*)d_in[0];
    const float* qkv_w  = (const float*)d_in[1];
    const float* qkv_b  = (const float*)d_in[2];
    const float* attn_w = (const float*)d_in[3];
    const float* attn_b = (const float*)d_in[4];
    const float* gate_w = (const float*)d_in[5];
    const float* gate_b = (const float*)d_in[6];
    const float* e_w1   = (const float*)d_in[7];
    const float* e_b1   = (const float*)d_in[8];
    const float* e_w2   = (const float*)d_in[9];
    const float* e_b2   = (const float*)d_in[10];
    const float* ln1_g  = (const float*)d_in[11];
    const float* ln1_b  = (const float*)d_in[12];
    const float* ln2_g  = (const float*)d_in[13];
    const float* ln2_b  = (const float*)d_in[14];
    const float* head_w = (const float*)d_in[15];
    const float* head_b = (const float*)d_in[16];
    float* out = (float*)d_out;
    float* wsf = (float*)d_ws;

    float* xb   = wsf + WS_X;
    float* lnb  = wsf + WS_LN;
    float* sob  = wsf + WS_SOUT;
    float* gv   = wsf + WS_GV;
    float* pp   = wsf + WS_PP;
    float* pool = wsf + WS_POOL;
    int*   ib   = (int*)(wsf + WS_INT);

    ushort* qkvsh = (ushort*)(wsf + WS_QKV);
    ushort* wT    = (ushort*)(wsf + WS_QKV);
    ushort* w1th  = wT;
    ushort* w2th  = wT + 4194304;
    ushort* wTdummy = wT + 6291456;

    ushort* vth = (ushort*)(wsf + WS_H);

    ushort* u16  = (ushort*)(wsf + WS_U16);
    ushort* lnh  = u16;
    ushort* qwh  = u16 + 4194304;
    ushort* awh  = u16 + 4587520;

    // ---- adaptive FFN chunking (h is bf16-only: NSLOT*hFF*2 bytes) ----
    size_t base_bytes = (size_t)WS_BIG * 4;
    int hFF = 256;
    if (ws_size >= base_bytes + (size_t)NSLOT * 1024 * 2)      hFF = 1024;
    else if (ws_size >= base_bytes + (size_t)NSLOT * 512 * 2)  hFF = 512;
    ushort* hh = (hFF == 256) ? (ushort*)(wsf + WS_H) : (ushort*)(wsf + WS_BIG);
    int NCC = 1024 / hFF;

    hipMemcpyAsync(xb, x, (size_t)TOK * DIM * sizeof(float), hipMemcpyDeviceToDevice, stream);

    for (int l = 0; l < NL; ++l) {
        // --- attention block ---
        ln_split<false><<<TOK / 4, 256, 0, stream>>>(xb, nullptr, lnh, ln1_g, ln1_b);
        split_transpose<false><<<dim3(8, 24, 1), 256, 0, stream>>>(
            qkv_w + (size_t)l * DIM * 3 * DIM, qwh, wTdummy, 256, 768);
        mfma_dense128x64<3><<<64 * 12, 256, 0, stream>>>(
            lnh, qwh, qkv_b + (size_t)l * 3 * DIM, nullptr, qkvsh, 768, 12);
        vt_kernel<<<dim3(32, 64), 256, 0, stream>>>(qkvsh, vth);
        attention_mfma<<<dim3(16, NH, 8), 256, 0, stream>>>(qkvsh, vth, lnh);
        split_transpose<false><<<dim3(8, 8, 1), 256, 0, stream>>>(
            attn_w + (size_t)l * DIM * DIM, awh, wTdummy, 256, 256);
        mfma_dense128x64<1><<<64 * 4, 256, 0, stream>>>(
            lnh, awh, attn_b + (size_t)l * DIM, xb, nullptr, 256, 4);

        // --- MoE block ---
        ln_split<true><<<TOK / 4, 256, 0, stream>>>(xb, lnb, lnh, ln2_g, ln2_b);
        split_transpose<false><<<dim3(8, 32, 8), 256, 0, stream>>>(
            e_w1 + (size_t)l * NE * DIM * FFD, w1th, wTdummy, 256, 1024);
        split_transpose<false><<<dim3(32, 8, 8), 256, 0, stream>>>(
            e_w2 + (size_t)l * NE * FFD * DIM, w2th, wTdummy, 1024, 256);
        gate_topk<<<TOK / 32, 256, 0, stream>>>(
            lnb, gate_w + (size_t)l * DIM * NE, gate_b + (size_t)l * NE, gv, ib);
        scan_tiles<<<1, 256, 0, stream>>>(ib);
        scatter_slots<<<TOK / 32, 64, 0, stream>>>(ib);
        for (int c = 0; c < NCC; ++c) {
            mfma_ffn1_12864<<<136 * (hFF / 64), 256, 0, stream>>>(
                lnh, w1th, e_b1 + (size_t)l * NE * FFD, hh, ib, c * hFF, hFF, hFF / 64);
            mfma_ffn2_12864<<<136 * 4, 256, 0, stream>>>(
                hh, w2th, e_b2 + (size_t)l * NE * DIM, sob, ib, c * hFF, hFF, 4);
        }
        moe_gather<<<TOK, 64, 0, stream>>>(xb, sob, gv, ib);
    }

    pool1<<<dim3(8, 32), 256, 0, stream>>>(xb, pp);
    pool2<<<8, 256, 0, stream>>>(pp, pool);
    head_kernel<<<4, 256, 0, stream>>>(pool, head_w, head_b, out);
}

// Round 31
// 332.452 us; speedup vs baseline: 1.1808x; 1.0046x over previous
//
#include <hip/hip_runtime.h>
#include <math.h>

#define TOK   8192
#define DIM   256
#define NH    8
#define HDIM  32
#define FFD   1024
#define NE    8
#define NL    2
#define NOUT  1000
#define NSLOT 16384   // TOK*2

typedef unsigned int uint;
typedef unsigned short ushort;
typedef __attribute__((ext_vector_type(8))) short short8;
typedef __attribute__((ext_vector_type(4))) float f32x4;

// ---------------- workspace layout (float units) ----------------
#define WS_X     ((size_t)0)
#define WS_LN    (WS_X    + (size_t)TOK*DIM)
#define WS_QKV   (WS_LN   + (size_t)TOK*DIM)
#define WS_H     (WS_QKV  + (size_t)TOK*3*DIM)
#define WS_SOUT  (WS_H    + (size_t)NSLOT*256)
#define WS_GV    (WS_SOUT + (size_t)NSLOT*256)
#define WS_PP    (WS_GV   + (size_t)TOK*2)
#define WS_POOL  (WS_PP   + (size_t)8*32*256)
#define WS_INT   (WS_POOL + (size_t)8*256)
#define WS_U16   (WS_INT  + (size_t)54144)
#define WS_BIG   (WS_U16  + (size_t)2359296)

// int region layout (int32 indices)
#define IB_COUNTS   0
#define IB_NTILES   8
#define IB_OFFS     16
#define IB_CURS     24
#define IB_TILE_E   32
#define IB_TILE_R0  320
#define IB_TILE_RE  608
#define IB_GIDX     896    // [TOK*2]
#define IB_SPOS     17280  // [TOK*2]
#define IB_STOK     33664  // [NSLOT]
#define IB_BLKC     50048  // [256*8]
#define IB_BLKB     52096  // [256*8]

// fast erf (Abramowitz-Stegun 7.1.26, |err| <= 1.5e-7) — error far below the
// bf16 rounding (2e-3 rel) applied to h right after.
__device__ __forceinline__ float gelu_exact(float v) {
    float z = v * 0.70710678118654752f;
    float s = fabsf(z);
    float t = __builtin_amdgcn_rcpf(1.0f + 0.3275911f * s);
    float p = ((((1.061405429f * t - 1.453152027f) * t + 1.421413741f) * t
                - 0.284496736f) * t + 0.254829592f) * t;
    float r = 1.0f - p * __expf(-s * s);
    float er = (z < 0.0f) ? -r : r;
    return 0.5f * v * (1.0f + er);
}

__device__ __forceinline__ ushort rnd_bf16(float x) {
    uint u = __float_as_uint(x);
    return (ushort)((u + 0x7FFFu + ((u >> 16) & 1u)) >> 16);
}

__device__ __forceinline__ void split2(float x, ushort& h, ushort& lo) {
    uint u = __float_as_uint(x);
    uint hh = (u + 0x7FFFu + ((u >> 16) & 1u)) >> 16;
    h = (ushort)hh;
    float hf = __uint_as_float(hh << 16);
    float l = x - hf;
    uint ul = __float_as_uint(l);
    lo = (ushort)((ul + 0x7FFFu + ((ul >> 16) & 1u)) >> 16);
}

// async global->LDS 16B: dest = wave-uniform base + lane*16 (linear); source per-lane.
__device__ __forceinline__ void gld16(const ushort* g, ushort* l) {
    __builtin_amdgcn_global_load_lds(
        (const __attribute__((address_space(1))) uint*)g,
        (__attribute__((address_space(3))) uint*)l, 16, 0, 0);
}

// XCD-aware decode: all NC col-blocks of a tile share bid%8 -> same XCD L2.
// Bijective for NT % 8 == 0. HW round-robins XCD by hardware block id.
__device__ __forceinline__ void xcd_map(int bid, int NC, int& t, int& j) {
    int g = bid >> 3;
    t = (bid & 7) + 8 * (g / NC);
    j = g % NC;
}

// ---------------- LayerNorm -> bf16 (hi-only) output (+optional f32) ----------------
template<bool WF32>
__global__ __launch_bounds__(256) void ln_split(const float* __restrict__ x,
                                                float* __restrict__ out,
                                                ushort* __restrict__ ohi,
                                                const float* __restrict__ g,
                                                const float* __restrict__ b) {
    int wave = threadIdx.x >> 6;
    int lane = threadIdx.x & 63;
    int t = blockIdx.x * 4 + wave;
    const float* xp = x + (size_t)t * DIM;
    float4 v = *(const float4*)&xp[lane * 4];
    float s = v.x + v.y + v.z + v.w;
    #pragma unroll
    for (int off = 32; off; off >>= 1) s += __shfl_xor(s, off);
    float mean = s * (1.0f / 256.0f);
    float dx = v.x - mean, dy = v.y - mean, dz = v.z - mean, dw = v.w - mean;
    float vs = dx * dx + dy * dy + dz * dz + dw * dw;
    #pragma unroll
    for (int off = 32; off; off >>= 1) vs += __shfl_xor(vs, off);
    float inv = rsqrtf(vs * (1.0f / 256.0f) + 1e-5f);
    float4 gg = *(const float4*)&g[lane * 4];
    float4 bb = *(const float4*)&b[lane * 4];
    float o0 = dx * inv * gg.x + bb.x;
    float o1 = dy * inv * gg.y + bb.y;
    float o2 = dz * inv * gg.z + bb.z;
    float o3 = dw * inv * gg.w + bb.w;
    size_t idx = (size_t)t * DIM + lane * 4;
    if (WF32) {
        float4 o; o.x = o0; o.y = o1; o.z = o2; o.w = o3;
        *(float4*)&out[idx] = o;
    }
    uint2 ph;
    ph.x = (uint)rnd_bf16(o0) | ((uint)rnd_bf16(o1) << 16);
    ph.y = (uint)rnd_bf16(o2) | ((uint)rnd_bf16(o3) << 16);
    *(uint2*)&ohi[idx] = ph;
}

// ---------------- split+transpose weights (WLO=false: hi only) ----------------
template<bool WLO>
__global__ __launch_bounds__(256) void split_transpose(const float* __restrict__ src,
                                                       ushort* __restrict__ dhi,
                                                       ushort* __restrict__ dlo,
                                                       int K, int N) {
    int z = blockIdx.z;
    const float* s = src + (size_t)z * K * N;
    ushort* th = dhi + (size_t)z * K * N;
    ushort* tl = dlo + (size_t)z * K * N;
    __shared__ float tile[32][33];
    int k0 = blockIdx.x * 32, n0 = blockIdx.y * 32;
    int tx = threadIdx.x & 31, ty = threadIdx.x >> 5;
    #pragma unroll
    for (int i = 0; i < 4; ++i) {
        int k = k0 + ty + i * 8;
        tile[ty + i * 8][tx] = s[(size_t)k * N + n0 + tx];
    }
    __syncthreads();
    #pragma unroll
    for (int i = 0; i < 4; ++i) {
        int n = n0 + ty + i * 8;
        float v = tile[tx][ty + i * 8];
        ushort h, lo;
        split2(v, h, lo);
        th[(size_t)n * K + k0 + tx] = h;
        if (WLO) tl[(size_t)n * K + k0 + tx] = lo;
    }
}

// ============ 128x64 GEMM core, BK=64, all hi-only, XCD-swizzled 1D grid ============
// MODE 0=f32 out, 1=f32+residual, 3=bf16 out. Grid = NT*NC blocks, NT%8==0.

template<int MODE>
__global__ __launch_bounds__(256) void mfma_dense128x64(const ushort* __restrict__ Ah,
                                                        const ushort* __restrict__ Bh,
                                                        const float* __restrict__ bias,
                                                        float* __restrict__ C,
                                                        ushort* __restrict__ Chi, int N, int NC) {
    __shared__ ushort LAh[128][64], LBh[64][64];
    int tT, tJ;
    xcd_map(blockIdx.x, NC, tT, tJ);
    int tid = threadIdx.x;
    int w = tid >> 6, l = tid & 63, c = l & 15, G = l >> 4;
    int row0 = tT * 128, col0 = tJ * 64;
    int lr = l >> 3, sd = l & 7;
    size_t gaA[4]; ushort* dA[4];
    size_t gbB[2]; ushort* dB[2];
    #pragma unroll
    for (int i = 0; i < 4; ++i) {
        int r = i * 32 + w * 8 + lr;
        gaA[i] = (size_t)(row0 + r) * 256 + ((sd ^ (r & 7)) << 3);
        dA[i] = &LAh[i * 32 + w * 8][0];
    }
    #pragma unroll
    for (int i = 0; i < 2; ++i) {
        int r = i * 32 + w * 8 + lr;
        gbB[i] = (size_t)(col0 + r) * 256 + ((sd ^ (r & 7)) << 3);
        dB[i] = &LBh[i * 32 + w * 8][0];
    }
    f32x4 acc[2][4] = {};
    for (int k0 = 0; k0 < 256; k0 += 64) {
        #pragma unroll
        for (int i = 0; i < 4; ++i) gld16(&Ah[gaA[i] + k0], dA[i]);
        #pragma unroll
        for (int i = 0; i < 2; ++i) gld16(&Bh[gbB[i] + k0], dB[i]);
        __syncthreads();
        #pragma unroll
        for (int s = 0; s < 2; ++s) {
            int ar = w * 32 + c;
            short8 a_h[2];
            #pragma unroll
            for (int i = 0; i < 2; ++i) {
                int r = ar + i * 16;
                int sg = (((s << 2) | G) ^ (r & 7)) << 3;
                a_h[i] = *(const short8*)&LAh[r][sg];
            }
            #pragma unroll
            for (int j = 0; j < 4; ++j) {
                int r = j * 16 + c;
                int sg = (((s << 2) | G) ^ (r & 7)) << 3;
                short8 b_h = *(const short8*)&LBh[r][sg];
                #pragma unroll
                for (int i = 0; i < 2; ++i) {
                    acc[i][j] = __builtin_amdgcn_mfma_f32_16x16x32_bf16(a_h[i], b_h, acc[i][j], 0, 0, 0);
                }
            }
        }
        __syncthreads();
    }
    int rbase = row0 + w * 32 + G * 4;
    #pragma unroll
    for (int i = 0; i < 2; ++i) {
        #pragma unroll
        for (int j = 0; j < 4; ++j) {
            int gc = col0 + j * 16 + c;
            float bv = bias[gc];
            #pragma unroll
            for (int rr = 0; rr < 4; ++rr) {
                int grow = rbase + i * 16 + rr;
                size_t idx = (size_t)grow * N + gc;
                float v = acc[i][j][rr] + bv;
                if (MODE == 1) v += C[idx];
                if (MODE == 3) {
                    Chi[idx] = rnd_bf16(v);
                } else {
                    C[idx] = v;
                }
            }
        }
    }
}

// ---------------- V transpose (hi-only) ----------------
__global__ __launch_bounds__(256) void vt_kernel(const ushort* __restrict__ qkvh,
                                                 ushort* __restrict__ vth) {
    int bh = blockIdx.y;
    int b = bh >> 3, h = bh & 7;
    int kv0 = blockIdx.x * 32;
    __shared__ ushort smh[32][33];
    int tid = threadIdx.x;
    #pragma unroll
    for (int p = 0; p < 4; ++p) {
        int kv = p * 8 + (tid >> 5);
        int d = tid & 31;
        size_t src = ((size_t)(b * 1024 + kv0 + kv)) * 768 + 512 + h * 32 + d;
        smh[kv][d] = qkvh[src];
    }
    __syncthreads();
    #pragma unroll
    for (int p = 0; p < 4; ++p) {
        int d = p * 8 + (tid >> 5);
        int kv = tid & 31;
        size_t dst = ((size_t)(bh * 32 + d)) * 1024 + kv0 + kv;
        vth[dst] = smh[kv][d];
    }
}

// ---------------- MFMA flash attention v8: KVBLK=128 + async-STAGE (T14) ----------------
// Global loads for tile i+1 issued right after the compute barrier; HBM/L2 latency
// hides under QK-MFMA + softmax + PV of tile i. Pure reordering: math identical.
__global__ __launch_bounds__(256, 4) void attention_mfma(const ushort* __restrict__ qkvh,
                                                         const ushort* __restrict__ vth,
                                                         ushort* __restrict__ ohi) {
    int b = blockIdx.z, h = blockIdx.y;
    int q0 = blockIdx.x * 64;
    int tid = threadIdx.x;
    int w = tid >> 6, l = tid & 63;
    int c = l & 15, g = l >> 4;
    __shared__ ushort Kh[128][40];
    __shared__ ushort VTh[32][136];
    __shared__ ushort Ph[4][16][140];

    size_t qbase = ((size_t)(b * 1024 + q0 + w * 16 + c)) * 768 + h * 32 + g * 8;
    short8 qa_h = *(const short8*)&qkvh[qbase];

    f32x4 acc_o[2] = {};
    float lpart[4] = {0.f, 0.f, 0.f, 0.f};
    const float scale = 0.17677669529663687f;

    int sr = tid >> 2, sc8 = (tid & 3) * 8;
    size_t kgbase = ((size_t)(b * 1024 + sr)) * 768 + 256 + h * 32 + sc8;
    int vd = tid >> 4, vk8 = (tid & 15) * 8;
    size_t vtbase = ((size_t)((b * 8 + h) * 32 + vd)) * 1024 + vk8;

    // prologue: load tile 0 into registers
    uint4 k0r = *(const uint4*)&qkvh[kgbase];
    uint4 k1r = *(const uint4*)&qkvh[kgbase + (size_t)64 * 768];
    uint4 v0r = *(const uint4*)&vth[vtbase];
    uint4 v1r = *(const uint4*)&vth[vtbase + 16 * 1024];

    for (int kv0 = 0; kv0 < 1024; kv0 += 128) {
        __syncthreads();
        *(uint4*)&Kh[sr][sc8]       = k0r;
        *(uint4*)&Kh[sr + 64][sc8]  = k1r;
        *(uint4*)&VTh[vd][vk8]      = v0r;
        *(uint4*)&VTh[vd + 16][vk8] = v1r;
        __syncthreads();

        // issue next tile's global loads now; latency hides under compute below
        if (kv0 + 128 < 1024) {
            k0r = *(const uint4*)&qkvh[kgbase + (size_t)(kv0 + 128) * 768];
            k1r = *(const uint4*)&qkvh[kgbase + (size_t)(kv0 + 192) * 768];
            v0r = *(const uint4*)&vth[vtbase + kv0 + 128];
            v1r = *(const uint4*)&vth[vtbase + 16 * 1024 + kv0 + 128];
        }

        f32x4 s4[8];
        #pragma unroll
        for (int t = 0; t < 8; ++t) {
            short8 kh = *(const short8*)&Kh[t * 16 + c][g * 8];
            f32x4 a = {};
            a = __builtin_amdgcn_mfma_f32_16x16x32_bf16(qa_h, kh, a, 0, 0, 0);
            s4[t] = a;
        }

        #pragma unroll
        for (int rr = 0; rr < 4; ++rr) {
            float sum = 0.f;
            #pragma unroll
            for (int t = 0; t < 8; ++t) {
                float p = __expf(s4[t][rr] * scale);
                uint u = __float_as_uint(p);
                uint r = (u + 0x7FFFu + ((u >> 16) & 1u)) >> 16;
                Ph[w][g * 4 + rr][t * 16 + c] = (ushort)r;
                sum += __uint_as_float(r << 16);
            }
            lpart[rr] += sum;
        }
        asm volatile("s_waitcnt lgkmcnt(0)" ::: "memory");

        #pragma unroll
        for (int kt = 0; kt < 4; ++kt) {
            short8 pah = *(const short8*)&Ph[w][c][kt * 32 + g * 8];
            #pragma unroll
            for (int T = 0; T < 2; ++T) {
                short8 vh = *(const short8*)&VTh[T * 16 + c][kt * 32 + g * 8];
                acc_o[T] = __builtin_amdgcn_mfma_f32_16x16x32_bf16(pah, vh, acc_o[T], 0, 0, 0);
            }
        }
    }

    #pragma unroll
    for (int rr = 0; rr < 4; ++rr) {
        float s = lpart[rr];
        s += __shfl_xor(s, 1);
        s += __shfl_xor(s, 2);
        s += __shfl_xor(s, 4);
        s += __shfl_xor(s, 8);
        lpart[rr] = s;
    }

    #pragma unroll
    for (int rr = 0; rr < 4; ++rr) {
        float inv = 1.0f / lpart[rr];
        int q = q0 + w * 16 + g * 4 + rr;
        #pragma unroll
        for (int T = 0; T < 2; ++T) {
            float v = acc_o[T][rr] * inv;
            size_t idx = (size_t)(b * 1024 + q) * 256 + h * 32 + T * 16 + c;
            ohi[idx] = rnd_bf16(v);
        }
    }
}

// ---------------- MFMA FFN1 128x64 BK=64, XCD-swizzled 1D grid ----------------
__global__ __launch_bounds__(256) void mfma_ffn1_12864(const ushort* __restrict__ Ah,
                                                       const ushort* __restrict__ W1h,
                                                       const float* __restrict__ b1l,
                                                       ushort* __restrict__ hh,
                                                       const int* __restrict__ ib,
                                                       int c0, int hFF, int NC) {
    int tileIdx, cj;
    xcd_map(blockIdx.x, NC, tileIdx, cj);
    if (tileIdx >= ib[IB_NTILES]) return;
    int e = ib[IB_TILE_E + tileIdx];
    int row0 = ib[IB_TILE_R0 + tileIdx];
    int rowend = ib[IB_TILE_RE + tileIdx];
    __shared__ ushort LAh[128][64], LBh[64][64];
    __shared__ int tok[128];
    int tid = threadIdx.x;
    if (tid < 128) {
        int sr = row0 + tid;
        tok[tid] = ib[IB_STOK + (sr < rowend ? sr : row0)];
    }
    __syncthreads();
    int w = tid >> 6, l = tid & 63, c = l & 15, G = l >> 4;
    int lr = l >> 3, sd = l & 7;
    int colbase = cj * 64;
    const ushort* Bh = W1h + (size_t)e * 262144 + (size_t)(c0 + colbase) * 256;
    size_t gaA[4]; ushort* dA[4];
    size_t gbB[2]; ushort* dB[2];
    #pragma unroll
    for (int i = 0; i < 4; ++i) {
        int r = i * 32 + w * 8 + lr;
        gaA[i] = (size_t)tok[r] * 256 + ((sd ^ (r & 7)) << 3);
        dA[i] = &LAh[i * 32 + w * 8][0];
    }
    #pragma unroll
    for (int i = 0; i < 2; ++i) {
        int r = i * 32 + w * 8 + lr;
        gbB[i] = (size_t)r * 256 + ((sd ^ (r & 7)) << 3);
        dB[i] = &LBh[i * 32 + w * 8][0];
    }
    f32x4 acc[2][4] = {};
    for (int k0 = 0; k0 < 256; k0 += 64) {
        #pragma unroll
        for (int i = 0; i < 4; ++i) gld16(&Ah[gaA[i] + k0], dA[i]);
        #pragma unroll
        for (int i = 0; i < 2; ++i) gld16(&Bh[gbB[i] + k0], dB[i]);
        __syncthreads();
        #pragma unroll
        for (int s = 0; s < 2; ++s) {
            int ar = w * 32 + c;
            short8 a_h[2];
            #pragma unroll
            for (int i = 0; i < 2; ++i) {
                int r = ar + i * 16;
                int sg = (((s << 2) | G) ^ (r & 7)) << 3;
                a_h[i] = *(const short8*)&LAh[r][sg];
            }
            #pragma unroll
            for (int j = 0; j < 4; ++j) {
                int r = j * 16 + c;
                int sg = (((s << 2) | G) ^ (r & 7)) << 3;
                short8 b_h = *(const short8*)&LBh[r][sg];
                #pragma unroll
                for (int i = 0; i < 2; ++i) {
                    acc[i][j] = __builtin_amdgcn_mfma_f32_16x16x32_bf16(a_h[i], b_h, acc[i][j], 0, 0, 0);
                }
            }
        }
        __syncthreads();
    }
    int rbase = row0 + w * 32 + G * 4;
    #pragma unroll
    for (int i = 0; i < 2; ++i) {
        #pragma unroll
        for (int j = 0; j < 4; ++j) {
            int cl = colbase + j * 16 + c;
            float bv = b1l[(size_t)e * FFD + c0 + cl];
            #pragma unroll
            for (int rr = 0; rr < 4; ++rr) {
                int sr = rbase + i * 16 + rr;
                if (sr < rowend) {
                    float v = gelu_exact(acc[i][j][rr] + bv);
                    hh[(size_t)sr * hFF + cl] = rnd_bf16(v);
                }
            }
        }
    }
}

// ---------------- MFMA FFN2 128x64 BK=64, XCD-swizzled 1D grid ----------------
__global__ __launch_bounds__(256) void mfma_ffn2_12864(const ushort* __restrict__ Ah,
                                                       const ushort* __restrict__ W2h,
                                                       const float* __restrict__ b2l,
                                                       float* __restrict__ sout,
                                                       const int* __restrict__ ib,
                                                       int c0, int hFF, int NC) {
    int tileIdx, cj;
    xcd_map(blockIdx.x, NC, tileIdx, cj);
    if (tileIdx >= ib[IB_NTILES]) return;
    int e = ib[IB_TILE_E + tileIdx];
    int row0 = ib[IB_TILE_R0 + tileIdx];
    int rowend = ib[IB_TILE_RE + tileIdx];
    __shared__ ushort LAh[128][64], LBh[64][64];
    int tid = threadIdx.x;
    int w = tid >> 6, l = tid & 63, c = l & 15, G = l >> 4;
    int lr = l >> 3, sd = l & 7;
    int colbase = cj * 64;
    const ushort* Bh = W2h + (size_t)e * 262144;
    size_t gaA[4]; ushort* dA[4];
    size_t gbB[2]; ushort* dB[2];
    #pragma unroll
    for (int i = 0; i < 4; ++i) {
        int r = i * 32 + w * 8 + lr;
        gaA[i] = (size_t)(row0 + r) * hFF + ((sd ^ (r & 7)) << 3);
        dA[i] = &LAh[i * 32 + w * 8][0];
    }
    #pragma unroll
    for (int i = 0; i < 2; ++i) {
        int r = i * 32 + w * 8 + lr;
        gbB[i] = (size_t)(colbase + r) * 1024 + c0 + ((sd ^ (r & 7)) << 3);
        dB[i] = &LBh[i * 32 + w * 8][0];
    }
    f32x4 acc[2][4] = {};
    for (int k0 = 0; k0 < hFF; k0 += 64) {
        #pragma unroll
        for (int i = 0; i < 4; ++i) gld16(&Ah[gaA[i] + k0], dA[i]);
        #pragma unroll
        for (int i = 0; i < 2; ++i) gld16(&Bh[gbB[i] + k0], dB[i]);
        __syncthreads();
        #pragma unroll
        for (int s = 0; s < 2; ++s) {
            int ar = w * 32 + c;
            short8 a_h[2];
            #pragma unroll
            for (int i = 0; i < 2; ++i) {
                int r = ar + i * 16;
                int sg = (((s << 2) | G) ^ (r & 7)) << 3;
                a_h[i] = *(const short8*)&LAh[r][sg];
            }
            #pragma unroll
            for (int j = 0; j < 4; ++j) {
                int r = j * 16 + c;
                int sg = (((s << 2) | G) ^ (r & 7)) << 3;
                short8 b_h = *(const short8*)&LBh[r][sg];
                #pragma unroll
                for (int i = 0; i < 2; ++i) {
                    acc[i][j] = __builtin_amdgcn_mfma_f32_16x16x32_bf16(a_h[i], b_h, acc[i][j], 0, 0, 0);
                }
            }
        }
        __syncthreads();
    }
    int rbase = row0 + w * 32 + G * 4;
    #pragma unroll
    for (int i = 0; i < 2; ++i) {
        #pragma unroll
        for (int j = 0; j < 4; ++j) {
            int n = colbase + j * 16 + c;
            float bv = b2l[(size_t)e * DIM + n];
            #pragma unroll
            for (int rr = 0; rr < 4; ++rr) {
                int sr = rbase + i * 16 + rr;
                if (sr < rowend) {
                    size_t idx = (size_t)sr * 256 + n;
                    if (c0 == 0) sout[idx] = acc[i][j][rr] + bv;
                    else         sout[idx] += acc[i][j][rr];
                }
            }
        }
    }
}

// ---------------- gate + top2 v3: LDS histogram, NO global atomics ----------------
__global__ __launch_bounds__(256) void gate_topk(const float* __restrict__ lnb,
                                                 const float* __restrict__ gw,
                                                 const float* __restrict__ gb,
                                                 float* __restrict__ gv, int* __restrict__ ib) {
    __shared__ int hist[8];
    int tid = threadIdx.x;
    if (tid < 8) hist[tid] = 0;
    __syncthreads();
    int grp = tid >> 3, ln8 = tid & 7;
    int t = blockIdx.x * 32 + grp;
    const float* x = lnb + (size_t)t * DIM + ln8 * 32;
    const float* wb = gw + (size_t)ln8 * 32 * 8;
    float g[8] = {};
    #pragma unroll
    for (int d4 = 0; d4 < 8; ++d4) {
        float4 xv = *(const float4*)&x[d4 * 4];
        const float* wr = wb + d4 * 32;
        float4 wa0 = *(const float4*)&wr[0],  wb0 = *(const float4*)&wr[4];
        float4 wa1 = *(const float4*)&wr[8],  wb1 = *(const float4*)&wr[12];
        float4 wa2 = *(const float4*)&wr[16], wb2 = *(const float4*)&wr[20];
        float4 wa3 = *(const float4*)&wr[24], wb3 = *(const float4*)&wr[28];
        g[0] += xv.x * wa0.x + xv.y * wa1.x + xv.z * wa2.x + xv.w * wa3.x;
        g[1] += xv.x * wa0.y + xv.y * wa1.y + xv.z * wa2.y + xv.w * wa3.y;
        g[2] += xv.x * wa0.z + xv.y * wa1.z + xv.z * wa2.z + xv.w * wa3.z;
        g[3] += xv.x * wa0.w + xv.y * wa1.w + xv.z * wa2.w + xv.w * wa3.w;
        g[4] += xv.x * wb0.x + xv.y * wb1.x + xv.z * wb2.x + xv.w * wb3.x;
        g[5] += xv.x * wb0.y + xv.y * wb1.y + xv.z * wb2.y + xv.w * wb3.y;
        g[6] += xv.x * wb0.z + xv.y * wb1.z + xv.z * wb2.z + xv.w * wb3.z;
        g[7] += xv.x * wb0.w + xv.y * wb1.w + xv.z * wb2.w + xv.w * wb3.w;
    }
    #pragma unroll
    for (int e = 0; e < 8; ++e) {
        g[e] += __shfl_xor(g[e], 1);
        g[e] += __shfl_xor(g[e], 2);
        g[e] += __shfl_xor(g[e], 4);
    }
    if (ln8 == 0) {
        #pragma unroll
        for (int e = 0; e < 8; ++e) g[e] += gb[e];
        int i0 = 0; float s0 = g[0];
        #pragma unroll
        for (int e = 1; e < 8; ++e) if (g[e] > s0) { s0 = g[e]; i0 = e; }
        int i1 = -1; float s1 = -1e30f;
        #pragma unroll
        for (int e = 0; e < 8; ++e) if (e != i0 && g[e] > s1) { s1 = g[e]; i1 = e; }
        float e1 = __expf(s1 - s0);
        float w0v = 1.0f / (1.0f + e1);
        float w1v = e1 / (1.0f + e1);
        gv[2 * t] = w0v; gv[2 * t + 1] = w1v;
        ib[IB_GIDX + 2 * t] = i0; ib[IB_GIDX + 2 * t + 1] = i1;
        atomicAdd(&hist[i0], 1);
        atomicAdd(&hist[i1], 1);
    }
    __syncthreads();
    if (tid < 8) ib[IB_BLKC + blockIdx.x * 8 + tid] = hist[tid];
}

// ---------------- scan: totals, offsets, per-block bases, tile table ----------------
__global__ __launch_bounds__(256) void scan_tiles(int* ib) {
    __shared__ int bc[2048], bb[2048];
    __shared__ int counts[8], offs[8], tstart[9];
    int tid = threadIdx.x;
    for (int i = tid; i < 2048; i += 256) bc[i] = ib[IB_BLKC + i];
    __syncthreads();
    if (tid < 8) {
        int run = 0;
        for (int b = 0; b < 256; ++b) {
            bb[b * 8 + tid] = run;
            run += bc[b * 8 + tid];
        }
        counts[tid] = run;
    }
    __syncthreads();
    if (tid == 0) {
        int off = 0, ts = 0;
        for (int e = 0; e < 8; ++e) {
            offs[e] = off;
            ib[IB_OFFS + e] = off;
            tstart[e] = ts;
            ib[IB_COUNTS + e] = counts[e];
            ts += (counts[e] + 127) >> 7;
            off += counts[e];
        }
        tstart[8] = ts;
        ib[IB_NTILES] = ts;
    }
    __syncthreads();
    for (int i = tid; i < 2048; i += 256)
        ib[IB_BLKB + i] = offs[i & 7] + bb[i];
    int total = tstart[8];
    for (int idx = tid; idx < total; idx += 256) {
        int e = 0;
        while (idx >= tstart[e + 1]) ++e;
        int i = idx - tstart[e];
        ib[IB_TILE_E + idx] = e;
        ib[IB_TILE_R0 + idx] = offs[e] + i * 128;
        int rem = counts[e] - i * 128;
        ib[IB_TILE_RE + idx] = offs[e] + i * 128 + (rem < 128 ? rem : 128);
    }
}

// ---------------- scatter to slots ----------------
__global__ __launch_bounds__(64) void scatter_slots(int* ib) {
    __shared__ int cnt8[8];
    int tid = threadIdx.x;
    if (tid < 8) cnt8[tid] = ib[IB_BLKB + blockIdx.x * 8 + tid];
    __syncthreads();
    int t = blockIdx.x * 32 + (tid >> 1);
    int k = tid & 1;
    int e = ib[IB_GIDX + 2 * t + k];
    int pos = atomicAdd(&cnt8[e], 1);
    ib[IB_STOK + pos] = t;
    ib[IB_SPOS + 2 * t + k] = pos;
}

// ---------------- gather ----------------
__global__ __launch_bounds__(64) void moe_gather(float* __restrict__ xb,
                                                 const float* __restrict__ sout,
                                                 const float* __restrict__ gv,
                                                 const int* __restrict__ ib) {
    int t = blockIdx.x;
    int d = threadIdx.x * 4;
    int p0 = ib[IB_SPOS + 2 * t], p1 = ib[IB_SPOS + 2 * t + 1];
    float g0 = gv[2 * t], g1 = gv[2 * t + 1];
    float4 xv = *(float4*)&xb[(size_t)t * 256 + d];
    float4 s0 = *(const float4*)&sout[(size_t)p0 * 256 + d];
    float4 s1 = *(const float4*)&sout[(size_t)p1 * 256 + d];
    xv.x += g0 * s0.x + g1 * s1.x;
    xv.y += g0 * s0.y + g1 * s1.y;
    xv.z += g0 * s0.z + g1 * s1.z;
    xv.w += g0 * s0.w + g1 * s1.w;
    *(float4*)&xb[(size_t)t * 256 + d] = xv;
}

// ---------------- pooling ----------------
__global__ __launch_bounds__(256) void pool1(const float* __restrict__ xb, float* __restrict__ pp) {
    int b = blockIdx.x, ch = blockIdx.y, d = threadIdx.x;
    float s = 0.0f;
    for (int i = 0; i < 32; ++i) s += xb[((size_t)b * 1024 + ch * 32 + i) * 256 + d];
    pp[(size_t)(b * 32 + ch) * 256 + d] = s;
}
__global__ __launch_bounds__(256) void pool2(const float* __restrict__ pp, float* __restrict__ pool) {
    int b = blockIdx.x, d = threadIdx.x;
    float s = 0.0f;
    for (int c = 0; c < 32; ++c) s += pp[(size_t)(b * 32 + c) * 256 + d];
    pool[(size_t)b * 256 + d] = s * (1.0f / 1024.0f);
}

// ---------------- head ----------------
__global__ __launch_bounds__(256) void head_kernel(const float* __restrict__ pool,
                                                   const float* __restrict__ hw,
                                                   const float* __restrict__ hb,
                                                   float* __restrict__ out) {
    __shared__ float P[2048];
    int tid = threadIdx.x;
    for (int i = tid; i < 2048; i += 256) P[i] = pool[i];
    __syncthreads();
    int j = blockIdx.x * 256 + tid;
    if (j >= NOUT) return;
    float acc[8] = {};
    for (int d = 0; d < 256; ++d) {
        float w = hw[(size_t)d * NOUT + j];
        #pragma unroll
        for (int b = 0; b < 8; ++b) acc[b] += P[b * 256 + d] * w;
    }
    #pragma unroll
    for (int b = 0; b < 8; ++b) out[(size_t)b * NOUT + j] = acc[b] + hb[j];
}

extern "C" void kernel_launch(void* const* d_in, const int* in_sizes, int n_in,
                              void* d_out, int out_size, void* d_ws, size_t ws_size,
                              hipStream_t stream) {
    const float* x      = (const float*)d_in[0];
    const float* qkv_w  = (const float*)d_in[1];
    const float* qkv_b  = (const float*)d_in[2];
    const float* attn_w = (const float*)d_in[3];
    const float* attn_b = (const float*)d_in[4];
    const float* gate_w = (const float*)d_in[5];
    const float* gate_b = (const float*)d_in[6];
    const float* e_w1   = (const float*)d_in[7];
    const float* e_b1   = (const float*)d_in[8];
    const float* e_w2   = (const float*)d_in[9];
    const float* e_b2   = (const float*)d_in[10];
    const float* ln1_g  = (const float*)d_in[11];
    const float* ln1_b  = (const float*)d_in[12];
    const float* ln2_g  = (const float*)d_in[13];
    const float* ln2_b  = (const float*)d_in[14];
    const float* head_w = (const float*)d_in[15];
    const float* head_b = (const float*)d_in[16];
    float* out = (float*)d_out;
    float* wsf = (float*)d_ws;

    float* xb   = wsf + WS_X;
    float* lnb  = wsf + WS_LN;
    float* sob  = wsf + WS_SOUT;
    float* gv   = wsf + WS_GV;
    float* pp   = wsf + WS_PP;
    float* pool = wsf + WS_POOL;
    int*   ib   = (int*)(wsf + WS_INT);

    ushort* qkvsh = (ushort*)(wsf + WS_QKV);
    ushort* wT    = (ushort*)(wsf + WS_QKV);
    ushort* w1th  = wT;
    ushort* w2th  = wT + 4194304;
    ushort* wTdummy = wT + 6291456;

    ushort* vth = (ushort*)(wsf + WS_H);

    ushort* u16  = (ushort*)(wsf + WS_U16);
    ushort* lnh  = u16;
    ushort* qwh  = u16 + 4194304;
    ushort* awh  = u16 + 4587520;

    // ---- adaptive FFN chunking (h is bf16-only: NSLOT*hFF*2 bytes) ----
    size_t base_bytes = (size_t)WS_BIG * 4;
    int hFF = 256;
    if (ws_size >= base_bytes + (size_t)NSLOT * 1024 * 2)      hFF = 1024;
    else if (ws_size >= base_bytes + (size_t)NSLOT * 512 * 2)  hFF = 512;
    ushort* hh = (hFF == 256) ? (ushort*)(wsf + WS_H) : (ushort*)(wsf + WS_BIG);
    int NCC = 1024 / hFF;

    hipMemcpyAsync(xb, x, (size_t)TOK * DIM * sizeof(float), hipMemcpyDeviceToDevice, stream);

    for (int l = 0; l < NL; ++l) {
        // --- attention block ---
        ln_split<false><<<TOK / 4, 256, 0, stream>>>(xb, nullptr, lnh, ln1_g, ln1_b);
        split_transpose<false><<<dim3(8, 24, 1), 256, 0, stream>>>(
            qkv_w + (size_t)l * DIM * 3 * DIM, qwh, wTdummy, 256, 768);
        mfma_dense128x64<3><<<64 * 12, 256, 0, stream>>>(
            lnh, qwh, qkv_b + (size_t)l * 3 * DIM, nullptr, qkvsh, 768, 12);
        vt_kernel<<<dim3(32, 64), 256, 0, stream>>>(qkvsh, vth);
        attention_mfma<<<dim3(16, NH, 8), 256, 0, stream>>>(qkvsh, vth, lnh);
        split_transpose<false><<<dim3(8, 8, 1), 256, 0, stream>>>(
            attn_w + (size_t)l * DIM * DIM, awh, wTdummy, 256, 256);
        mfma_dense128x64<1><<<64 * 4, 256, 0, stream>>>(
            lnh, awh, attn_b + (size_t)l * DIM, xb, nullptr, 256, 4);

        // --- MoE block ---
        ln_split<true><<<TOK / 4, 256, 0, stream>>>(xb, lnb, lnh, ln2_g, ln2_b);
        split_transpose<false><<<dim3(8, 32, 8), 256, 0, stream>>>(
            e_w1 + (size_t)l * NE * DIM * FFD, w1th, wTdummy, 256, 1024);
        split_transpose<false><<<dim3(32, 8, 8), 256, 0, stream>>>(
            e_w2 + (size_t)l * NE * FFD * DIM, w2th, wTdummy, 1024, 256);
        gate_topk<<<TOK / 32, 256, 0, stream>>>(
            lnb, gate_w + (size_t)l * DIM * NE, gate_b + (size_t)l * NE, gv, ib);
        scan_tiles<<<1, 256, 0, stream>>>(ib);
        scatter_slots<<<TOK / 32, 64, 0, stream>>>(ib);
        for (int c = 0; c < NCC; ++c) {
            mfma_ffn1_12864<<<136 * (hFF / 64), 256, 0, stream>>>(
                lnh, w1th, e_b1 + (size_t)l * NE * FFD, hh, ib, c * hFF, hFF, hFF / 64);
            mfma_ffn2_12864<<<136 * 4, 256, 0, stream>>>(
                hh, w2th, e_b2 + (size_t)l * NE * DIM, sob, ib, c * hFF, hFF, 4);
        }
        moe_gather<<<TOK, 64, 0, stream>>>(xb, sob, gv, ib);
    }

    pool1<<<dim3(8, 32), 256, 0, stream>>>(xb, pp);
    pool2<<<8, 256, 0, stream>>>(pp, pool);
    head_kernel<<<4, 256, 0, stream>>>(pool, head_w, head_b, out);
}

// Round 32
// 322.077 us; speedup vs baseline: 1.2189x; 1.0322x over previous
//
#include <hip/hip_runtime.h>
#include <math.h>

#define TOK   8192
#define DIM   256
#define NH    8
#define HDIM  32
#define FFD   1024
#define NE    8
#define NL    2
#define NOUT  1000
#define NSLOT 16384   // TOK*2

typedef unsigned int uint;
typedef unsigned short ushort;
typedef __attribute__((ext_vector_type(8))) short short8;
typedef __attribute__((ext_vector_type(4))) float f32x4;

// ---------------- workspace layout (float units) ----------------
#define WS_X     ((size_t)0)
#define WS_LN    (WS_X    + (size_t)TOK*DIM)
#define WS_QKV   (WS_LN   + (size_t)TOK*DIM)
#define WS_H     (WS_QKV  + (size_t)TOK*3*DIM)
#define WS_SOUT  (WS_H    + (size_t)NSLOT*256)
#define WS_GV    (WS_SOUT + (size_t)NSLOT*256)
#define WS_PP    (WS_GV   + (size_t)TOK*2)
#define WS_POOL  (WS_PP   + (size_t)8*32*256)
#define WS_INT   (WS_POOL + (size_t)8*256)
#define WS_U16   (WS_INT  + (size_t)54144)
#define WS_BIG   (WS_U16  + (size_t)2359296)

// int region layout (int32 indices)
#define IB_COUNTS   0
#define IB_NTILES   8
#define IB_OFFS     16
#define IB_CURS     24
#define IB_TILE_E   32
#define IB_TILE_R0  320
#define IB_TILE_RE  608
#define IB_GIDX     896    // [TOK*2]
#define IB_SPOS     17280  // [TOK*2]
#define IB_STOK     33664  // [NSLOT]
#define IB_BLKC     50048  // [256*8]
#define IB_BLKB     52096  // [256*8]

// fast erf (Abramowitz-Stegun 7.1.26, |err| <= 1.5e-7) — error far below the
// bf16 rounding (2e-3 rel) applied to h right after.
__device__ __forceinline__ float gelu_exact(float v) {
    float z = v * 0.70710678118654752f;
    float s = fabsf(z);
    float t = __builtin_amdgcn_rcpf(1.0f + 0.3275911f * s);
    float p = ((((1.061405429f * t - 1.453152027f) * t + 1.421413741f) * t
                - 0.284496736f) * t + 0.254829592f) * t;
    float r = 1.0f - p * __expf(-s * s);
    float er = (z < 0.0f) ? -r : r;
    return 0.5f * v * (1.0f + er);
}

__device__ __forceinline__ ushort rnd_bf16(float x) {
    uint u = __float_as_uint(x);
    return (ushort)((u + 0x7FFFu + ((u >> 16) & 1u)) >> 16);
}

// async global->LDS 16B: dest = wave-uniform base + lane*16 (linear); source per-lane.
__device__ __forceinline__ void gld16(const ushort* g, ushort* l) {
    __builtin_amdgcn_global_load_lds(
        (const __attribute__((address_space(1))) uint*)g,
        (__attribute__((address_space(3))) uint*)l, 16, 0, 0);
}

// XCD-aware decode: all NC col-blocks of a tile share bid%8 -> same XCD L2.
// Bijective for NT % 8 == 0. HW round-robins XCD by hardware block id.
__device__ __forceinline__ void xcd_map(int bid, int NC, int& t, int& j) {
    int g = bid >> 3;
    t = (bid & 7) + 8 * (g / NC);
    j = g % NC;
}

// ---------------- LayerNorm -> bf16 (hi-only) output (+optional f32) ----------------
template<bool WF32>
__global__ __launch_bounds__(256) void ln_split(const float* __restrict__ x,
                                                float* __restrict__ out,
                                                ushort* __restrict__ ohi,
                                                const float* __restrict__ g,
                                                const float* __restrict__ b) {
    int wave = threadIdx.x >> 6;
    int lane = threadIdx.x & 63;
    int t = blockIdx.x * 4 + wave;
    const float* xp = x + (size_t)t * DIM;
    float4 v = *(const float4*)&xp[lane * 4];
    float s = v.x + v.y + v.z + v.w;
    #pragma unroll
    for (int off = 32; off; off >>= 1) s += __shfl_xor(s, off);
    float mean = s * (1.0f / 256.0f);
    float dx = v.x - mean, dy = v.y - mean, dz = v.z - mean, dw = v.w - mean;
    float vs = dx * dx + dy * dy + dz * dz + dw * dw;
    #pragma unroll
    for (int off = 32; off; off >>= 1) vs += __shfl_xor(vs, off);
    float inv = rsqrtf(vs * (1.0f / 256.0f) + 1e-5f);
    float4 gg = *(const float4*)&g[lane * 4];
    float4 bb = *(const float4*)&b[lane * 4];
    float o0 = dx * inv * gg.x + bb.x;
    float o1 = dy * inv * gg.y + bb.y;
    float o2 = dz * inv * gg.z + bb.z;
    float o3 = dw * inv * gg.w + bb.w;
    size_t idx = (size_t)t * DIM + lane * 4;
    if (WF32) {
        float4 o; o.x = o0; o.y = o1; o.z = o2; o.w = o3;
        *(float4*)&out[idx] = o;
    }
    uint2 ph;
    ph.x = (uint)rnd_bf16(o0) | ((uint)rnd_bf16(o1) << 16);
    ph.y = (uint)rnd_bf16(o2) | ((uint)rnd_bf16(o3) << 16);
    *(uint2*)&ohi[idx] = ph;
}

// ---------------- fused attention-weight transposes: qkv_w (y<24) + attn_w ----------------
__global__ __launch_bounds__(256) void st_attn_weights(const float* __restrict__ qkvw,
                                                       const float* __restrict__ attnw,
                                                       ushort* __restrict__ qwh,
                                                       ushort* __restrict__ awh) {
    __shared__ float tile[32][33];
    int y = blockIdx.y;
    const float* s; ushort* th; int N, n0;
    int K = 256, k0 = blockIdx.x * 32;
    if (y < 24) { s = qkvw;  th = qwh; N = 768; n0 = y * 32; }
    else        { s = attnw; th = awh; N = 256; n0 = (y - 24) * 32; }
    int tx = threadIdx.x & 31, ty = threadIdx.x >> 5;
    #pragma unroll
    for (int i = 0; i < 4; ++i) {
        int k = k0 + ty + i * 8;
        tile[ty + i * 8][tx] = s[(size_t)k * N + n0 + tx];
    }
    __syncthreads();
    #pragma unroll
    for (int i = 0; i < 4; ++i) {
        int n = n0 + ty + i * 8;
        th[(size_t)n * K + k0 + tx] = rnd_bf16(tile[tx][ty + i * 8]);
    }
}

// ---------------- fused expert-weight transposes: w1 (idx<256) + w2, hi-only ----------------
__global__ __launch_bounds__(256) void st_expert_weights(const float* __restrict__ w1,
                                                         const float* __restrict__ w2,
                                                         ushort* __restrict__ w1th,
                                                         ushort* __restrict__ w2th) {
    __shared__ float tile[32][33];
    int z = blockIdx.y;
    int idx = blockIdx.x;
    const float* s; ushort* th; int K, N, k0, n0;
    if (idx < 256) {
        s = w1 + (size_t)z * 262144; th = w1th + (size_t)z * 262144;
        K = 256; N = 1024; k0 = (idx & 7) * 32; n0 = (idx >> 3) * 32;
    } else {
        idx -= 256;
        s = w2 + (size_t)z * 262144; th = w2th + (size_t)z * 262144;
        K = 1024; N = 256; k0 = (idx & 31) * 32; n0 = (idx >> 5) * 32;
    }
    int tx = threadIdx.x & 31, ty = threadIdx.x >> 5;
    #pragma unroll
    for (int i = 0; i < 4; ++i) {
        int k = k0 + ty + i * 8;
        tile[ty + i * 8][tx] = s[(size_t)k * N + n0 + tx];
    }
    __syncthreads();
    #pragma unroll
    for (int i = 0; i < 4; ++i) {
        int n = n0 + ty + i * 8;
        th[(size_t)n * K + k0 + tx] = rnd_bf16(tile[tx][ty + i * 8]);
    }
}

// ============ 128x64 GEMM core, BK=64, all hi-only, XCD-swizzled 1D grid ============
// MODE 0=f32 out, 1=f32+residual, 3=bf16 out. Grid = NT*NC blocks, NT%8==0.

template<int MODE>
__global__ __launch_bounds__(256) void mfma_dense128x64(const ushort* __restrict__ Ah,
                                                        const ushort* __restrict__ Bh,
                                                        const float* __restrict__ bias,
                                                        float* __restrict__ C,
                                                        ushort* __restrict__ Chi, int N, int NC) {
    __shared__ ushort LAh[128][64], LBh[64][64];
    int tT, tJ;
    xcd_map(blockIdx.x, NC, tT, tJ);
    int tid = threadIdx.x;
    int w = tid >> 6, l = tid & 63, c = l & 15, G = l >> 4;
    int row0 = tT * 128, col0 = tJ * 64;
    int lr = l >> 3, sd = l & 7;
    size_t gaA[4]; ushort* dA[4];
    size_t gbB[2]; ushort* dB[2];
    #pragma unroll
    for (int i = 0; i < 4; ++i) {
        int r = i * 32 + w * 8 + lr;
        gaA[i] = (size_t)(row0 + r) * 256 + ((sd ^ (r & 7)) << 3);
        dA[i] = &LAh[i * 32 + w * 8][0];
    }
    #pragma unroll
    for (int i = 0; i < 2; ++i) {
        int r = i * 32 + w * 8 + lr;
        gbB[i] = (size_t)(col0 + r) * 256 + ((sd ^ (r & 7)) << 3);
        dB[i] = &LBh[i * 32 + w * 8][0];
    }
    f32x4 acc[2][4] = {};
    for (int k0 = 0; k0 < 256; k0 += 64) {
        #pragma unroll
        for (int i = 0; i < 4; ++i) gld16(&Ah[gaA[i] + k0], dA[i]);
        #pragma unroll
        for (int i = 0; i < 2; ++i) gld16(&Bh[gbB[i] + k0], dB[i]);
        __syncthreads();
        #pragma unroll
        for (int s = 0; s < 2; ++s) {
            int ar = w * 32 + c;
            short8 a_h[2];
            #pragma unroll
            for (int i = 0; i < 2; ++i) {
                int r = ar + i * 16;
                int sg = (((s << 2) | G) ^ (r & 7)) << 3;
                a_h[i] = *(const short8*)&LAh[r][sg];
            }
            #pragma unroll
            for (int j = 0; j < 4; ++j) {
                int r = j * 16 + c;
                int sg = (((s << 2) | G) ^ (r & 7)) << 3;
                short8 b_h = *(const short8*)&LBh[r][sg];
                #pragma unroll
                for (int i = 0; i < 2; ++i) {
                    acc[i][j] = __builtin_amdgcn_mfma_f32_16x16x32_bf16(a_h[i], b_h, acc[i][j], 0, 0, 0);
                }
            }
        }
        __syncthreads();
    }
    int rbase = row0 + w * 32 + G * 4;
    #pragma unroll
    for (int i = 0; i < 2; ++i) {
        #pragma unroll
        for (int j = 0; j < 4; ++j) {
            int gc = col0 + j * 16 + c;
            float bv = bias[gc];
            #pragma unroll
            for (int rr = 0; rr < 4; ++rr) {
                int grow = rbase + i * 16 + rr;
                size_t idx = (size_t)grow * N + gc;
                float v = acc[i][j][rr] + bv;
                if (MODE == 1) v += C[idx];
                if (MODE == 3) {
                    Chi[idx] = rnd_bf16(v);
                } else {
                    C[idx] = v;
                }
            }
        }
    }
}

// ---------------- V transpose (hi-only) ----------------
__global__ __launch_bounds__(256) void vt_kernel(const ushort* __restrict__ qkvh,
                                                 ushort* __restrict__ vth) {
    int bh = blockIdx.y;
    int b = bh >> 3, h = bh & 7;
    int kv0 = blockIdx.x * 32;
    __shared__ ushort smh[32][33];
    int tid = threadIdx.x;
    #pragma unroll
    for (int p = 0; p < 4; ++p) {
        int kv = p * 8 + (tid >> 5);
        int d = tid & 31;
        size_t src = ((size_t)(b * 1024 + kv0 + kv)) * 768 + 512 + h * 32 + d;
        smh[kv][d] = qkvh[src];
    }
    __syncthreads();
    #pragma unroll
    for (int p = 0; p < 4; ++p) {
        int d = p * 8 + (tid >> 5);
        int kv = tid & 31;
        size_t dst = ((size_t)(bh * 32 + d)) * 1024 + kv0 + kv;
        vth[dst] = smh[kv][d];
    }
}

// ---------------- MFMA flash attention v8: KVBLK=128 + async-STAGE (T14) ----------------
__global__ __launch_bounds__(256, 4) void attention_mfma(const ushort* __restrict__ qkvh,
                                                         const ushort* __restrict__ vth,
                                                         ushort* __restrict__ ohi) {
    int b = blockIdx.z, h = blockIdx.y;
    int q0 = blockIdx.x * 64;
    int tid = threadIdx.x;
    int w = tid >> 6, l = tid & 63;
    int c = l & 15, g = l >> 4;
    __shared__ ushort Kh[128][40];
    __shared__ ushort VTh[32][136];
    __shared__ ushort Ph[4][16][140];

    size_t qbase = ((size_t)(b * 1024 + q0 + w * 16 + c)) * 768 + h * 32 + g * 8;
    short8 qa_h = *(const short8*)&qkvh[qbase];

    f32x4 acc_o[2] = {};
    float lpart[4] = {0.f, 0.f, 0.f, 0.f};
    const float scale = 0.17677669529663687f;

    int sr = tid >> 2, sc8 = (tid & 3) * 8;
    size_t kgbase = ((size_t)(b * 1024 + sr)) * 768 + 256 + h * 32 + sc8;
    int vd = tid >> 4, vk8 = (tid & 15) * 8;
    size_t vtbase = ((size_t)((b * 8 + h) * 32 + vd)) * 1024 + vk8;

    uint4 k0r = *(const uint4*)&qkvh[kgbase];
    uint4 k1r = *(const uint4*)&qkvh[kgbase + (size_t)64 * 768];
    uint4 v0r = *(const uint4*)&vth[vtbase];
    uint4 v1r = *(const uint4*)&vth[vtbase + 16 * 1024];

    for (int kv0 = 0; kv0 < 1024; kv0 += 128) {
        __syncthreads();
        *(uint4*)&Kh[sr][sc8]       = k0r;
        *(uint4*)&Kh[sr + 64][sc8]  = k1r;
        *(uint4*)&VTh[vd][vk8]      = v0r;
        *(uint4*)&VTh[vd + 16][vk8] = v1r;
        __syncthreads();

        if (kv0 + 128 < 1024) {
            k0r = *(const uint4*)&qkvh[kgbase + (size_t)(kv0 + 128) * 768];
            k1r = *(const uint4*)&qkvh[kgbase + (size_t)(kv0 + 192) * 768];
            v0r = *(const uint4*)&vth[vtbase + kv0 + 128];
            v1r = *(const uint4*)&vth[vtbase + 16 * 1024 + kv0 + 128];
        }

        f32x4 s4[8];
        #pragma unroll
        for (int t = 0; t < 8; ++t) {
            short8 kh = *(const short8*)&Kh[t * 16 + c][g * 8];
            f32x4 a = {};
            a = __builtin_amdgcn_mfma_f32_16x16x32_bf16(qa_h, kh, a, 0, 0, 0);
            s4[t] = a;
        }

        #pragma unroll
        for (int rr = 0; rr < 4; ++rr) {
            float sum = 0.f;
            #pragma unroll
            for (int t = 0; t < 8; ++t) {
                float p = __expf(s4[t][rr] * scale);
                uint u = __float_as_uint(p);
                uint r = (u + 0x7FFFu + ((u >> 16) & 1u)) >> 16;
                Ph[w][g * 4 + rr][t * 16 + c] = (ushort)r;
                sum += __uint_as_float(r << 16);
            }
            lpart[rr] += sum;
        }
        asm volatile("s_waitcnt lgkmcnt(0)" ::: "memory");

        #pragma unroll
        for (int kt = 0; kt < 4; ++kt) {
            short8 pah = *(const short8*)&Ph[w][c][kt * 32 + g * 8];
            #pragma unroll
            for (int T = 0; T < 2; ++T) {
                short8 vh = *(const short8*)&VTh[T * 16 + c][kt * 32 + g * 8];
                acc_o[T] = __builtin_amdgcn_mfma_f32_16x16x32_bf16(pah, vh, acc_o[T], 0, 0, 0);
            }
        }
    }

    #pragma unroll
    for (int rr = 0; rr < 4; ++rr) {
        float s = lpart[rr];
        s += __shfl_xor(s, 1);
        s += __shfl_xor(s, 2);
        s += __shfl_xor(s, 4);
        s += __shfl_xor(s, 8);
        lpart[rr] = s;
    }

    #pragma unroll
    for (int rr = 0; rr < 4; ++rr) {
        float inv = 1.0f / lpart[rr];
        int q = q0 + w * 16 + g * 4 + rr;
        #pragma unroll
        for (int T = 0; T < 2; ++T) {
            float v = acc_o[T][rr] * inv;
            size_t idx = (size_t)(b * 1024 + q) * 256 + h * 32 + T * 16 + c;
            ohi[idx] = rnd_bf16(v);
        }
    }
}

// ---------------- MFMA FFN1 128x64 BK=64, XCD-swizzled 1D grid ----------------
__global__ __launch_bounds__(256) void mfma_ffn1_12864(const ushort* __restrict__ Ah,
                                                       const ushort* __restrict__ W1h,
                                                       const float* __restrict__ b1l,
                                                       ushort* __restrict__ hh,
                                                       const int* __restrict__ ib,
                                                       int c0, int hFF, int NC) {
    int tileIdx, cj;
    xcd_map(blockIdx.x, NC, tileIdx, cj);
    if (tileIdx >= ib[IB_NTILES]) return;
    int e = ib[IB_TILE_E + tileIdx];
    int row0 = ib[IB_TILE_R0 + tileIdx];
    int rowend = ib[IB_TILE_RE + tileIdx];
    __shared__ ushort LAh[128][64], LBh[64][64];
    __shared__ int tok[128];
    int tid = threadIdx.x;
    if (tid < 128) {
        int sr = row0 + tid;
        tok[tid] = ib[IB_STOK + (sr < rowend ? sr : row0)];
    }
    __syncthreads();
    int w = tid >> 6, l = tid & 63, c = l & 15, G = l >> 4;
    int lr = l >> 3, sd = l & 7;
    int colbase = cj * 64;
    const ushort* Bh = W1h + (size_t)e * 262144 + (size_t)(c0 + colbase) * 256;
    size_t gaA[4]; ushort* dA[4];
    size_t gbB[2]; ushort* dB[2];
    #pragma unroll
    for (int i = 0; i < 4; ++i) {
        int r = i * 32 + w * 8 + lr;
        gaA[i] = (size_t)tok[r] * 256 + ((sd ^ (r & 7)) << 3);
        dA[i] = &LAh[i * 32 + w * 8][0];
    }
    #pragma unroll
    for (int i = 0; i < 2; ++i) {
        int r = i * 32 + w * 8 + lr;
        gbB[i] = (size_t)r * 256 + ((sd ^ (r & 7)) << 3);
        dB[i] = &LBh[i * 32 + w * 8][0];
    }
    f32x4 acc[2][4] = {};
    for (int k0 = 0; k0 < 256; k0 += 64) {
        #pragma unroll
        for (int i = 0; i < 4; ++i) gld16(&Ah[gaA[i] + k0], dA[i]);
        #pragma unroll
        for (int i = 0; i < 2; ++i) gld16(&Bh[gbB[i] + k0], dB[i]);
        __syncthreads();
        #pragma unroll
        for (int s = 0; s < 2; ++s) {
            int ar = w * 32 + c;
            short8 a_h[2];
            #pragma unroll
            for (int i = 0; i < 2; ++i) {
                int r = ar + i * 16;
                int sg = (((s << 2) | G) ^ (r & 7)) << 3;
                a_h[i] = *(const short8*)&LAh[r][sg];
            }
            #pragma unroll
            for (int j = 0; j < 4; ++j) {
                int r = j * 16 + c;
                int sg = (((s << 2) | G) ^ (r & 7)) << 3;
                short8 b_h = *(const short8*)&LBh[r][sg];
                #pragma unroll
                for (int i = 0; i < 2; ++i) {
                    acc[i][j] = __builtin_amdgcn_mfma_f32_16x16x32_bf16(a_h[i], b_h, acc[i][j], 0, 0, 0);
                }
            }
        }
        __syncthreads();
    }
    int rbase = row0 + w * 32 + G * 4;
    #pragma unroll
    for (int i = 0; i < 2; ++i) {
        #pragma unroll
        for (int j = 0; j < 4; ++j) {
            int cl = colbase + j * 16 + c;
            float bv = b1l[(size_t)e * FFD + c0 + cl];
            #pragma unroll
            for (int rr = 0; rr < 4; ++rr) {
                int sr = rbase + i * 16 + rr;
                if (sr < rowend) {
                    float v = gelu_exact(acc[i][j][rr] + bv);
                    hh[(size_t)sr * hFF + cl] = rnd_bf16(v);
                }
            }
        }
    }
}

// ---------------- MFMA FFN2 128x64 BK=64, XCD-swizzled 1D grid ----------------
__global__ __launch_bounds__(256) void mfma_ffn2_12864(const ushort* __restrict__ Ah,
                                                       const ushort* __restrict__ W2h,
                                                       const float* __restrict__ b2l,
                                                       float* __restrict__ sout,
                                                       const int* __restrict__ ib,
                                                       int c0, int hFF, int NC) {
    int tileIdx, cj;
    xcd_map(blockIdx.x, NC, tileIdx, cj);
    if (tileIdx >= ib[IB_NTILES]) return;
    int e = ib[IB_TILE_E + tileIdx];
    int row0 = ib[IB_TILE_R0 + tileIdx];
    int rowend = ib[IB_TILE_RE + tileIdx];
    __shared__ ushort LAh[128][64], LBh[64][64];
    int tid = threadIdx.x;
    int w = tid >> 6, l = tid & 63, c = l & 15, G = l >> 4;
    int lr = l >> 3, sd = l & 7;
    int colbase = cj * 64;
    const ushort* Bh = W2h + (size_t)e * 262144;
    size_t gaA[4]; ushort* dA[4];
    size_t gbB[2]; ushort* dB[2];
    #pragma unroll
    for (int i = 0; i < 4; ++i) {
        int r = i * 32 + w * 8 + lr;
        gaA[i] = (size_t)(row0 + r) * hFF + ((sd ^ (r & 7)) << 3);
        dA[i] = &LAh[i * 32 + w * 8][0];
    }
    #pragma unroll
    for (int i = 0; i < 2; ++i) {
        int r = i * 32 + w * 8 + lr;
        gbB[i] = (size_t)(colbase + r) * 1024 + c0 + ((sd ^ (r & 7)) << 3);
        dB[i] = &LBh[i * 32 + w * 8][0];
    }
    f32x4 acc[2][4] = {};
    for (int k0 = 0; k0 < hFF; k0 += 64) {
        #pragma unroll
        for (int i = 0; i < 4; ++i) gld16(&Ah[gaA[i] + k0], dA[i]);
        #pragma unroll
        for (int i = 0; i < 2; ++i) gld16(&Bh[gbB[i] + k0], dB[i]);
        __syncthreads();
        #pragma unroll
        for (int s = 0; s < 2; ++s) {
            int ar = w * 32 + c;
            short8 a_h[2];
            #pragma unroll
            for (int i = 0; i < 2; ++i) {
                int r = ar + i * 16;
                int sg = (((s << 2) | G) ^ (r & 7)) << 3;
                a_h[i] = *(const short8*)&LAh[r][sg];
            }
            #pragma unroll
            for (int j = 0; j < 4; ++j) {
                int r = j * 16 + c;
                int sg = (((s << 2) | G) ^ (r & 7)) << 3;
                short8 b_h = *(const short8*)&LBh[r][sg];
                #pragma unroll
                for (int i = 0; i < 2; ++i) {
                    acc[i][j] = __builtin_amdgcn_mfma_f32_16x16x32_bf16(a_h[i], b_h, acc[i][j], 0, 0, 0);
                }
            }
        }
        __syncthreads();
    }
    int rbase = row0 + w * 32 + G * 4;
    #pragma unroll
    for (int i = 0; i < 2; ++i) {
        #pragma unroll
        for (int j = 0; j < 4; ++j) {
            int n = colbase + j * 16 + c;
            float bv = b2l[(size_t)e * DIM + n];
            #pragma unroll
            for (int rr = 0; rr < 4; ++rr) {
                int sr = rbase + i * 16 + rr;
                if (sr < rowend) {
                    size_t idx = (size_t)sr * 256 + n;
                    if (c0 == 0) sout[idx] = acc[i][j][rr] + bv;
                    else         sout[idx] += acc[i][j][rr];
                }
            }
        }
    }
}

// ---------------- gate + top2 v3: LDS histogram, NO global atomics ----------------
__global__ __launch_bounds__(256) void gate_topk(const float* __restrict__ lnb,
                                                 const float* __restrict__ gw,
                                                 const float* __restrict__ gb,
                                                 float* __restrict__ gv, int* __restrict__ ib) {
    __shared__ int hist[8];
    int tid = threadIdx.x;
    if (tid < 8) hist[tid] = 0;
    __syncthreads();
    int grp = tid >> 3, ln8 = tid & 7;
    int t = blockIdx.x * 32 + grp;
    const float* x = lnb + (size_t)t * DIM + ln8 * 32;
    const float* wb = gw + (size_t)ln8 * 32 * 8;
    float g[8] = {};
    #pragma unroll
    for (int d4 = 0; d4 < 8; ++d4) {
        float4 xv = *(const float4*)&x[d4 * 4];
        const float* wr = wb + d4 * 32;
        float4 wa0 = *(const float4*)&wr[0],  wb0 = *(const float4*)&wr[4];
        float4 wa1 = *(const float4*)&wr[8],  wb1 = *(const float4*)&wr[12];
        float4 wa2 = *(const float4*)&wr[16], wb2 = *(const float4*)&wr[20];
        float4 wa3 = *(const float4*)&wr[24], wb3 = *(const float4*)&wr[28];
        g[0] += xv.x * wa0.x + xv.y * wa1.x + xv.z * wa2.x + xv.w * wa3.x;
        g[1] += xv.x * wa0.y + xv.y * wa1.y + xv.z * wa2.y + xv.w * wa3.y;
        g[2] += xv.x * wa0.z + xv.y * wa1.z + xv.z * wa2.z + xv.w * wa3.z;
        g[3] += xv.x * wa0.w + xv.y * wa1.w + xv.z * wa2.w + xv.w * wa3.w;
        g[4] += xv.x * wb0.x + xv.y * wb1.x + xv.z * wb2.x + xv.w * wb3.x;
        g[5] += xv.x * wb0.y + xv.y * wb1.y + xv.z * wb2.y + xv.w * wb3.y;
        g[6] += xv.x * wb0.z + xv.y * wb1.z + xv.z * wb2.z + xv.w * wb3.z;
        g[7] += xv.x * wb0.w + xv.y * wb1.w + xv.z * wb2.w + xv.w * wb3.w;
    }
    #pragma unroll
    for (int e = 0; e < 8; ++e) {
        g[e] += __shfl_xor(g[e], 1);
        g[e] += __shfl_xor(g[e], 2);
        g[e] += __shfl_xor(g[e], 4);
    }
    if (ln8 == 0) {
        #pragma unroll
        for (int e = 0; e < 8; ++e) g[e] += gb[e];
        int i0 = 0; float s0 = g[0];
        #pragma unroll
        for (int e = 1; e < 8; ++e) if (g[e] > s0) { s0 = g[e]; i0 = e; }
        int i1 = -1; float s1 = -1e30f;
        #pragma unroll
        for (int e = 0; e < 8; ++e) if (e != i0 && g[e] > s1) { s1 = g[e]; i1 = e; }
        float e1 = __expf(s1 - s0);
        float w0v = 1.0f / (1.0f + e1);
        float w1v = e1 / (1.0f + e1);
        gv[2 * t] = w0v; gv[2 * t + 1] = w1v;
        ib[IB_GIDX + 2 * t] = i0; ib[IB_GIDX + 2 * t + 1] = i1;
        atomicAdd(&hist[i0], 1);
        atomicAdd(&hist[i1], 1);
    }
    __syncthreads();
    if (tid < 8) ib[IB_BLKC + blockIdx.x * 8 + tid] = hist[tid];
}

// ---------------- scan: totals, offsets, per-block bases, tile table ----------------
__global__ __launch_bounds__(256) void scan_tiles(int* ib) {
    __shared__ int bc[2048], bb[2048];
    __shared__ int counts[8], offs[8], tstart[9];
    int tid = threadIdx.x;
    for (int i = tid; i < 2048; i += 256) bc[i] = ib[IB_BLKC + i];
    __syncthreads();
    if (tid < 8) {
        int run = 0;
        for (int b = 0; b < 256; ++b) {
            bb[b * 8 + tid] = run;
            run += bc[b * 8 + tid];
        }
        counts[tid] = run;
    }
    __syncthreads();
    if (tid == 0) {
        int off = 0, ts = 0;
        for (int e = 0; e < 8; ++e) {
            offs[e] = off;
            ib[IB_OFFS + e] = off;
            tstart[e] = ts;
            ib[IB_COUNTS + e] = counts[e];
            ts += (counts[e] + 127) >> 7;
            off += counts[e];
        }
        tstart[8] = ts;
        ib[IB_NTILES] = ts;
    }
    __syncthreads();
    for (int i = tid; i < 2048; i += 256)
        ib[IB_BLKB + i] = offs[i & 7] + bb[i];
    int total = tstart[8];
    for (int idx = tid; idx < total; idx += 256) {
        int e = 0;
        while (idx >= tstart[e + 1]) ++e;
        int i = idx - tstart[e];
        ib[IB_TILE_E + idx] = e;
        ib[IB_TILE_R0 + idx] = offs[e] + i * 128;
        int rem = counts[e] - i * 128;
        ib[IB_TILE_RE + idx] = offs[e] + i * 128 + (rem < 128 ? rem : 128);
    }
}

// ---------------- scatter to slots ----------------
__global__ __launch_bounds__(64) void scatter_slots(int* ib) {
    __shared__ int cnt8[8];
    int tid = threadIdx.x;
    if (tid < 8) cnt8[tid] = ib[IB_BLKB + blockIdx.x * 8 + tid];
    __syncthreads();
    int t = blockIdx.x * 32 + (tid >> 1);
    int k = tid & 1;
    int e = ib[IB_GIDX + 2 * t + k];
    int pos = atomicAdd(&cnt8[e], 1);
    ib[IB_STOK + pos] = t;
    ib[IB_SPOS + 2 * t + k] = pos;
}

// ---------------- gather (+ optional fused next-layer LN1, bit-identical to ln_split) ----------------
template<bool WLN>
__global__ __launch_bounds__(64) void moe_gather(float* __restrict__ xb,
                                                 const float* __restrict__ sout,
                                                 const float* __restrict__ gv,
                                                 const int* __restrict__ ib,
                                                 ushort* __restrict__ ohi,
                                                 const float* __restrict__ g,
                                                 const float* __restrict__ b) {
    int t = blockIdx.x;
    int d = threadIdx.x * 4;
    int p0 = ib[IB_SPOS + 2 * t], p1 = ib[IB_SPOS + 2 * t + 1];
    float g0 = gv[2 * t], g1 = gv[2 * t + 1];
    float4 xv = *(float4*)&xb[(size_t)t * 256 + d];
    float4 s0 = *(const float4*)&sout[(size_t)p0 * 256 + d];
    float4 s1 = *(const float4*)&sout[(size_t)p1 * 256 + d];
    xv.x += g0 * s0.x + g1 * s1.x;
    xv.y += g0 * s0.y + g1 * s1.y;
    xv.z += g0 * s0.z + g1 * s1.z;
    xv.w += g0 * s0.w + g1 * s1.w;
    *(float4*)&xb[(size_t)t * 256 + d] = xv;
    if (WLN) {
        float s = xv.x + xv.y + xv.z + xv.w;
        #pragma unroll
        for (int off = 32; off; off >>= 1) s += __shfl_xor(s, off);
        float mean = s * (1.0f / 256.0f);
        float dx = xv.x - mean, dy = xv.y - mean, dz = xv.z - mean, dw = xv.w - mean;
        float vs = dx * dx + dy * dy + dz * dz + dw * dw;
        #pragma unroll
        for (int off = 32; off; off >>= 1) vs += __shfl_xor(vs, off);
        float inv = rsqrtf(vs * (1.0f / 256.0f) + 1e-5f);
        float4 gg = *(const float4*)&g[d];
        float4 bb = *(const float4*)&b[d];
        float o0 = dx * inv * gg.x + bb.x;
        float o1 = dy * inv * gg.y + bb.y;
        float o2 = dz * inv * gg.z + bb.z;
        float o3 = dw * inv * gg.w + bb.w;
        uint2 ph;
        ph.x = (uint)rnd_bf16(o0) | ((uint)rnd_bf16(o1) << 16);
        ph.y = (uint)rnd_bf16(o2) | ((uint)rnd_bf16(o3) << 16);
        *(uint2*)&ohi[(size_t)t * 256 + d] = ph;
    }
}

// ---------------- pooling ----------------
__global__ __launch_bounds__(256) void pool1(const float* __restrict__ xb, float* __restrict__ pp) {
    int b = blockIdx.x, ch = blockIdx.y, d = threadIdx.x;
    float s = 0.0f;
    for (int i = 0; i < 32; ++i) s += xb[((size_t)b * 1024 + ch * 32 + i) * 256 + d];
    pp[(size_t)(b * 32 + ch) * 256 + d] = s;
}
__global__ __launch_bounds__(256) void pool2(const float* __restrict__ pp, float* __restrict__ pool) {
    int b = blockIdx.x, d = threadIdx.x;
    float s = 0.0f;
    for (int c = 0; c < 32; ++c) s += pp[(size_t)(b * 32 + c) * 256 + d];
    pool[(size_t)b * 256 + d] = s * (1.0f / 1024.0f);
}

// ---------------- head ----------------
__global__ __launch_bounds__(256) void head_kernel(const float* __restrict__ pool,
                                                   const float* __restrict__ hw,
                                                   const float* __restrict__ hb,
                                                   float* __restrict__ out) {
    __shared__ float P[2048];
    int tid = threadIdx.x;
    for (int i = tid; i < 2048; i += 256) P[i] = pool[i];
    __syncthreads();
    int j = blockIdx.x * 256 + tid;
    if (j >= NOUT) return;
    float acc[8] = {};
    for (int d = 0; d < 256; ++d) {
        float w = hw[(size_t)d * NOUT + j];
        #pragma unroll
        for (int b = 0; b < 8; ++b) acc[b] += P[b * 256 + d] * w;
    }
    #pragma unroll
    for (int b = 0; b < 8; ++b) out[(size_t)b * NOUT + j] = acc[b] + hb[j];
}

extern "C" void kernel_launch(void* const* d_in, const int* in_sizes, int n_in,
                              void* d_out, int out_size, void* d_ws, size_t ws_size,
                              hipStream_t stream) {
    const float* x      = (const float*)d_in[0];
    const float* qkv_w  = (const float*)d_in[1];
    const float* qkv_b  = (const float*)d_in[2];
    const float* attn_w = (const float*)d_in[3];
    const float* attn_b = (const float*)d_in[4];
    const float* gate_w = (const float*)d_in[5];
    const float* gate_b = (const float*)d_in[6];
    const float* e_w1   = (const float*)d_in[7];
    const float* e_b1   = (const float*)d_in[8];
    const float* e_w2   = (const float*)d_in[9];
    const float* e_b2   = (const float*)d_in[10];
    const float* ln1_g  = (const float*)d_in[11];
    const float* ln1_b  = (const float*)d_in[12];
    const float* ln2_g  = (const float*)d_in[13];
    const float* ln2_b  = (const float*)d_in[14];
    const float* head_w = (const float*)d_in[15];
    const float* head_b = (const float*)d_in[16];
    float* out = (float*)d_out;
    float* wsf = (float*)d_ws;

    float* xb   = wsf + WS_X;
    float* lnb  = wsf + WS_LN;
    float* sob  = wsf + WS_SOUT;
    float* gv   = wsf + WS_GV;
    float* pp   = wsf + WS_PP;
    float* pool = wsf + WS_POOL;
    int*   ib   = (int*)(wsf + WS_INT);

    ushort* qkvsh = (ushort*)(wsf + WS_QKV);
    ushort* wT    = (ushort*)(wsf + WS_QKV);
    ushort* w1th  = wT;
    ushort* w2th  = wT + 4194304;

    ushort* vth = (ushort*)(wsf + WS_H);

    ushort* u16  = (ushort*)(wsf + WS_U16);
    ushort* lnh  = u16;
    ushort* qwh  = u16 + 4194304;
    ushort* awh  = u16 + 4587520;

    // ---- adaptive FFN chunking (h is bf16-only: NSLOT*hFF*2 bytes) ----
    size_t base_bytes = (size_t)WS_BIG * 4;
    int hFF = 256;
    if (ws_size >= base_bytes + (size_t)NSLOT * 1024 * 2)      hFF = 1024;
    else if (ws_size >= base_bytes + (size_t)NSLOT * 512 * 2)  hFF = 512;
    ushort* hh = (hFF == 256) ? (ushort*)(wsf + WS_H) : (ushort*)(wsf + WS_BIG);
    int NCC = 1024 / hFF;

    hipMemcpyAsync(xb, x, (size_t)TOK * DIM * sizeof(float), hipMemcpyDeviceToDevice, stream);

    for (int l = 0; l < NL; ++l) {
        // --- attention block ---
        if (l == 0)
            ln_split<false><<<TOK / 4, 256, 0, stream>>>(xb, nullptr, lnh, ln1_g, ln1_b);
        st_attn_weights<<<dim3(8, 32), 256, 0, stream>>>(
            qkv_w + (size_t)l * DIM * 3 * DIM, attn_w + (size_t)l * DIM * DIM, qwh, awh);
        mfma_dense128x64<3><<<64 * 12, 256, 0, stream>>>(
            lnh, qwh, qkv_b + (size_t)l * 3 * DIM, nullptr, qkvsh, 768, 12);
        vt_kernel<<<dim3(32, 64), 256, 0, stream>>>(qkvsh, vth);
        attention_mfma<<<dim3(16, NH, 8), 256, 0, stream>>>(qkvsh, vth, lnh);
        mfma_dense128x64<1><<<64 * 4, 256, 0, stream>>>(
            lnh, awh, attn_b + (size_t)l * DIM, xb, nullptr, 256, 4);

        // --- MoE block ---
        ln_split<true><<<TOK / 4, 256, 0, stream>>>(xb, lnb, lnh, ln2_g, ln2_b);
        st_expert_weights<<<dim3(512, 8), 256, 0, stream>>>(
            e_w1 + (size_t)l * NE * DIM * FFD, e_w2 + (size_t)l * NE * FFD * DIM, w1th, w2th);
        gate_topk<<<TOK / 32, 256, 0, stream>>>(
            lnb, gate_w + (size_t)l * DIM * NE, gate_b + (size_t)l * NE, gv, ib);
        scan_tiles<<<1, 256, 0, stream>>>(ib);
        scatter_slots<<<TOK / 32, 64, 0, stream>>>(ib);
        for (int c = 0; c < NCC; ++c) {
            mfma_ffn1_12864<<<136 * (hFF / 64), 256, 0, stream>>>(
                lnh, w1th, e_b1 + (size_t)l * NE * FFD, hh, ib, c * hFF, hFF, hFF / 64);
            mfma_ffn2_12864<<<136 * 4, 256, 0, stream>>>(
                hh, w2th, e_b2 + (size_t)l * NE * DIM, sob, ib, c * hFF, hFF, 4);
        }
        if (l + 1 < NL)
            moe_gather<true><<<TOK, 64, 0, stream>>>(xb, sob, gv, ib, lnh, ln1_g, ln1_b);
        else
            moe_gather<false><<<TOK, 64, 0, stream>>>(xb, sob, gv, ib, nullptr, nullptr, nullptr);
    }

    pool1<<<dim3(8, 32), 256, 0, stream>>>(xb, pp);
    pool2<<<8, 256, 0, stream>>>(pp, pool);
    head_kernel<<<4, 256, 0, stream>>>(pool, head_w, head_b, out);
}

// Round 33
// 318.547 us; speedup vs baseline: 1.2324x; 1.0111x over previous
//
#include <hip/hip_runtime.h>
#include <math.h>

#define TOK   8192
#define DIM   256
#define NH    8
#define HDIM  32
#define FFD   1024
#define NE    8
#define NL    2
#define NOUT  1000
#define NSLOT 16384   // TOK*2

typedef unsigned int uint;
typedef unsigned short ushort;
typedef __attribute__((ext_vector_type(8))) short short8;
typedef __attribute__((ext_vector_type(4))) float f32x4;

// ---------------- workspace layout (float units) ----------------
#define WS_X     ((size_t)0)
#define WS_LN    (WS_X    + (size_t)TOK*DIM)
#define WS_QKV   (WS_LN   + (size_t)TOK*DIM)
#define WS_H     (WS_QKV  + (size_t)TOK*3*DIM)
#define WS_SOUT  (WS_H    + (size_t)NSLOT*256)
#define WS_GV    (WS_SOUT + (size_t)NSLOT*256)
#define WS_PP    (WS_GV   + (size_t)TOK*2)
#define WS_POOL  (WS_PP   + (size_t)8*32*256)
#define WS_INT   (WS_POOL + (size_t)8*256)
#define WS_U16   (WS_INT  + (size_t)54144)
#define WS_BIG   (WS_U16  + (size_t)2359296)

// int region layout (int32 indices)
#define IB_COUNTS   0
#define IB_NTILES   8
#define IB_OFFS     16
#define IB_CURS     24
#define IB_TILE_E   32
#define IB_TILE_R0  320
#define IB_TILE_RE  608
#define IB_GIDX     896    // [TOK*2]
#define IB_SPOS     17280  // [TOK*2]
#define IB_STOK     33664  // [NSLOT]
#define IB_BLKC     50048  // [256*8]
#define IB_BLKB     52096  // [256*8]

// fast erf (Abramowitz-Stegun 7.1.26, |err| <= 1.5e-7) — error far below the
// bf16 rounding (2e-3 rel) applied to h right after.
__device__ __forceinline__ float gelu_exact(float v) {
    float z = v * 0.70710678118654752f;
    float s = fabsf(z);
    float t = __builtin_amdgcn_rcpf(1.0f + 0.3275911f * s);
    float p = ((((1.061405429f * t - 1.453152027f) * t + 1.421413741f) * t
                - 0.284496736f) * t + 0.254829592f) * t;
    float r = 1.0f - p * __expf(-s * s);
    float er = (z < 0.0f) ? -r : r;
    return 0.5f * v * (1.0f + er);
}

__device__ __forceinline__ ushort rnd_bf16(float x) {
    uint u = __float_as_uint(x);
    return (ushort)((u + 0x7FFFu + ((u >> 16) & 1u)) >> 16);
}

__device__ __forceinline__ float bf16_f32(ushort h) {
    return __uint_as_float(((uint)h) << 16);
}

// async global->LDS 16B: dest = wave-uniform base + lane*16 (linear); source per-lane.
__device__ __forceinline__ void gld16(const ushort* g, ushort* l) {
    __builtin_amdgcn_global_load_lds(
        (const __attribute__((address_space(1))) uint*)g,
        (__attribute__((address_space(3))) uint*)l, 16, 0, 0);
}

// XCD-aware decode: all NC col-blocks of a tile share bid%8 -> same XCD L2.
// Bijective for NT % 8 == 0. HW round-robins XCD by hardware block id.
__device__ __forceinline__ void xcd_map(int bid, int NC, int& t, int& j) {
    int g = bid >> 3;
    t = (bid & 7) + 8 * (g / NC);
    j = g % NC;
}

// ---------------- LayerNorm -> bf16 (hi-only) output (+optional f32) ----------------
template<bool WF32>
__global__ __launch_bounds__(256) void ln_split(const float* __restrict__ x,
                                                float* __restrict__ out,
                                                ushort* __restrict__ ohi,
                                                const float* __restrict__ g,
                                                const float* __restrict__ b) {
    int wave = threadIdx.x >> 6;
    int lane = threadIdx.x & 63;
    int t = blockIdx.x * 4 + wave;
    const float* xp = x + (size_t)t * DIM;
    float4 v = *(const float4*)&xp[lane * 4];
    float s = v.x + v.y + v.z + v.w;
    #pragma unroll
    for (int off = 32; off; off >>= 1) s += __shfl_xor(s, off);
    float mean = s * (1.0f / 256.0f);
    float dx = v.x - mean, dy = v.y - mean, dz = v.z - mean, dw = v.w - mean;
    float vs = dx * dx + dy * dy + dz * dz + dw * dw;
    #pragma unroll
    for (int off = 32; off; off >>= 1) vs += __shfl_xor(vs, off);
    float inv = rsqrtf(vs * (1.0f / 256.0f) + 1e-5f);
    float4 gg = *(const float4*)&g[lane * 4];
    float4 bb = *(const float4*)&b[lane * 4];
    float o0 = dx * inv * gg.x + bb.x;
    float o1 = dy * inv * gg.y + bb.y;
    float o2 = dz * inv * gg.z + bb.z;
    float o3 = dw * inv * gg.w + bb.w;
    size_t idx = (size_t)t * DIM + lane * 4;
    if (WF32) {
        float4 o; o.x = o0; o.y = o1; o.z = o2; o.w = o3;
        *(float4*)&out[idx] = o;
    }
    uint2 ph;
    ph.x = (uint)rnd_bf16(o0) | ((uint)rnd_bf16(o1) << 16);
    ph.y = (uint)rnd_bf16(o2) | ((uint)rnd_bf16(o3) << 16);
    *(uint2*)&ohi[idx] = ph;
}

// ---------------- fused attention-weight transposes: qkv_w (y<24) + attn_w ----------------
__global__ __launch_bounds__(256) void st_attn_weights(const float* __restrict__ qkvw,
                                                       const float* __restrict__ attnw,
                                                       ushort* __restrict__ qwh,
                                                       ushort* __restrict__ awh) {
    __shared__ float tile[32][33];
    int y = blockIdx.y;
    const float* s; ushort* th; int N, n0;
    int K = 256, k0 = blockIdx.x * 32;
    if (y < 24) { s = qkvw;  th = qwh; N = 768; n0 = y * 32; }
    else        { s = attnw; th = awh; N = 256; n0 = (y - 24) * 32; }
    int tx = threadIdx.x & 31, ty = threadIdx.x >> 5;
    #pragma unroll
    for (int i = 0; i < 4; ++i) {
        int k = k0 + ty + i * 8;
        tile[ty + i * 8][tx] = s[(size_t)k * N + n0 + tx];
    }
    __syncthreads();
    #pragma unroll
    for (int i = 0; i < 4; ++i) {
        int n = n0 + ty + i * 8;
        th[(size_t)n * K + k0 + tx] = rnd_bf16(tile[tx][ty + i * 8]);
    }
}

// ---------------- fused expert-weight transposes: w1 (idx<256) + w2, hi-only ----------------
__global__ __launch_bounds__(256) void st_expert_weights(const float* __restrict__ w1,
                                                         const float* __restrict__ w2,
                                                         ushort* __restrict__ w1th,
                                                         ushort* __restrict__ w2th) {
    __shared__ float tile[32][33];
    int z = blockIdx.y;
    int idx = blockIdx.x;
    const float* s; ushort* th; int K, N, k0, n0;
    if (idx < 256) {
        s = w1 + (size_t)z * 262144; th = w1th + (size_t)z * 262144;
        K = 256; N = 1024; k0 = (idx & 7) * 32; n0 = (idx >> 3) * 32;
    } else {
        idx -= 256;
        s = w2 + (size_t)z * 262144; th = w2th + (size_t)z * 262144;
        K = 1024; N = 256; k0 = (idx & 31) * 32; n0 = (idx >> 5) * 32;
    }
    int tx = threadIdx.x & 31, ty = threadIdx.x >> 5;
    #pragma unroll
    for (int i = 0; i < 4; ++i) {
        int k = k0 + ty + i * 8;
        tile[ty + i * 8][tx] = s[(size_t)k * N + n0 + tx];
    }
    __syncthreads();
    #pragma unroll
    for (int i = 0; i < 4; ++i) {
        int n = n0 + ty + i * 8;
        th[(size_t)n * K + k0 + tx] = rnd_bf16(tile[tx][ty + i * 8]);
    }
}

// ============ 128x64 GEMM core, BK=64, all hi-only, XCD-swizzled 1D grid ============
// MODE 0=f32 out, 1=f32+residual, 3=bf16 out. Grid = NT*NC blocks, NT%8==0.

template<int MODE>
__global__ __launch_bounds__(256) void mfma_dense128x64(const ushort* __restrict__ Ah,
                                                        const ushort* __restrict__ Bh,
                                                        const float* __restrict__ bias,
                                                        float* __restrict__ C,
                                                        ushort* __restrict__ Chi, int N, int NC) {
    __shared__ ushort LAh[128][64], LBh[64][64];
    int tT, tJ;
    xcd_map(blockIdx.x, NC, tT, tJ);
    int tid = threadIdx.x;
    int w = tid >> 6, l = tid & 63, c = l & 15, G = l >> 4;
    int row0 = tT * 128, col0 = tJ * 64;
    int lr = l >> 3, sd = l & 7;
    size_t gaA[4]; ushort* dA[4];
    size_t gbB[2]; ushort* dB[2];
    #pragma unroll
    for (int i = 0; i < 4; ++i) {
        int r = i * 32 + w * 8 + lr;
        gaA[i] = (size_t)(row0 + r) * 256 + ((sd ^ (r & 7)) << 3);
        dA[i] = &LAh[i * 32 + w * 8][0];
    }
    #pragma unroll
    for (int i = 0; i < 2; ++i) {
        int r = i * 32 + w * 8 + lr;
        gbB[i] = (size_t)(col0 + r) * 256 + ((sd ^ (r & 7)) << 3);
        dB[i] = &LBh[i * 32 + w * 8][0];
    }
    f32x4 acc[2][4] = {};
    for (int k0 = 0; k0 < 256; k0 += 64) {
        #pragma unroll
        for (int i = 0; i < 4; ++i) gld16(&Ah[gaA[i] + k0], dA[i]);
        #pragma unroll
        for (int i = 0; i < 2; ++i) gld16(&Bh[gbB[i] + k0], dB[i]);
        __syncthreads();
        #pragma unroll
        for (int s = 0; s < 2; ++s) {
            int ar = w * 32 + c;
            short8 a_h[2];
            #pragma unroll
            for (int i = 0; i < 2; ++i) {
                int r = ar + i * 16;
                int sg = (((s << 2) | G) ^ (r & 7)) << 3;
                a_h[i] = *(const short8*)&LAh[r][sg];
            }
            #pragma unroll
            for (int j = 0; j < 4; ++j) {
                int r = j * 16 + c;
                int sg = (((s << 2) | G) ^ (r & 7)) << 3;
                short8 b_h = *(const short8*)&LBh[r][sg];
                #pragma unroll
                for (int i = 0; i < 2; ++i) {
                    acc[i][j] = __builtin_amdgcn_mfma_f32_16x16x32_bf16(a_h[i], b_h, acc[i][j], 0, 0, 0);
                }
            }
        }
        __syncthreads();
    }
    int rbase = row0 + w * 32 + G * 4;
    #pragma unroll
    for (int i = 0; i < 2; ++i) {
        #pragma unroll
        for (int j = 0; j < 4; ++j) {
            int gc = col0 + j * 16 + c;
            float bv = bias[gc];
            #pragma unroll
            for (int rr = 0; rr < 4; ++rr) {
                int grow = rbase + i * 16 + rr;
                size_t idx = (size_t)grow * N + gc;
                float v = acc[i][j][rr] + bv;
                if (MODE == 1) v += C[idx];
                if (MODE == 3) {
                    Chi[idx] = rnd_bf16(v);
                } else {
                    C[idx] = v;
                }
            }
        }
    }
}

// ---------------- V transpose (hi-only) ----------------
__global__ __launch_bounds__(256) void vt_kernel(const ushort* __restrict__ qkvh,
                                                 ushort* __restrict__ vth) {
    int bh = blockIdx.y;
    int b = bh >> 3, h = bh & 7;
    int kv0 = blockIdx.x * 32;
    __shared__ ushort smh[32][33];
    int tid = threadIdx.x;
    #pragma unroll
    for (int p = 0; p < 4; ++p) {
        int kv = p * 8 + (tid >> 5);
        int d = tid & 31;
        size_t src = ((size_t)(b * 1024 + kv0 + kv)) * 768 + 512 + h * 32 + d;
        smh[kv][d] = qkvh[src];
    }
    __syncthreads();
    #pragma unroll
    for (int p = 0; p < 4; ++p) {
        int d = p * 8 + (tid >> 5);
        int kv = tid & 31;
        size_t dst = ((size_t)(bh * 32 + d)) * 1024 + kv0 + kv;
        vth[dst] = smh[kv][d];
    }
}

// ---------------- MFMA flash attention v8: KVBLK=128 + async-STAGE (T14) ----------------
__global__ __launch_bounds__(256, 4) void attention_mfma(const ushort* __restrict__ qkvh,
                                                         const ushort* __restrict__ vth,
                                                         ushort* __restrict__ ohi) {
    int b = blockIdx.z, h = blockIdx.y;
    int q0 = blockIdx.x * 64;
    int tid = threadIdx.x;
    int w = tid >> 6, l = tid & 63;
    int c = l & 15, g = l >> 4;
    __shared__ ushort Kh[128][40];
    __shared__ ushort VTh[32][136];
    __shared__ ushort Ph[4][16][140];

    size_t qbase = ((size_t)(b * 1024 + q0 + w * 16 + c)) * 768 + h * 32 + g * 8;
    short8 qa_h = *(const short8*)&qkvh[qbase];

    f32x4 acc_o[2] = {};
    float lpart[4] = {0.f, 0.f, 0.f, 0.f};
    const float scale = 0.17677669529663687f;

    int sr = tid >> 2, sc8 = (tid & 3) * 8;
    size_t kgbase = ((size_t)(b * 1024 + sr)) * 768 + 256 + h * 32 + sc8;
    int vd = tid >> 4, vk8 = (tid & 15) * 8;
    size_t vtbase = ((size_t)((b * 8 + h) * 32 + vd)) * 1024 + vk8;

    uint4 k0r = *(const uint4*)&qkvh[kgbase];
    uint4 k1r = *(const uint4*)&qkvh[kgbase + (size_t)64 * 768];
    uint4 v0r = *(const uint4*)&vth[vtbase];
    uint4 v1r = *(const uint4*)&vth[vtbase + 16 * 1024];

    for (int kv0 = 0; kv0 < 1024; kv0 += 128) {
        __syncthreads();
        *(uint4*)&Kh[sr][sc8]       = k0r;
        *(uint4*)&Kh[sr + 64][sc8]  = k1r;
        *(uint4*)&VTh[vd][vk8]      = v0r;
        *(uint4*)&VTh[vd + 16][vk8] = v1r;
        __syncthreads();

        if (kv0 + 128 < 1024) {
            k0r = *(const uint4*)&qkvh[kgbase + (size_t)(kv0 + 128) * 768];
            k1r = *(const uint4*)&qkvh[kgbase + (size_t)(kv0 + 192) * 768];
            v0r = *(const uint4*)&vth[vtbase + kv0 + 128];
            v1r = *(const uint4*)&vth[vtbase + 16 * 1024 + kv0 + 128];
        }

        f32x4 s4[8];
        #pragma unroll
        for (int t = 0; t < 8; ++t) {
            short8 kh = *(const short8*)&Kh[t * 16 + c][g * 8];
            f32x4 a = {};
            a = __builtin_amdgcn_mfma_f32_16x16x32_bf16(qa_h, kh, a, 0, 0, 0);
            s4[t] = a;
        }

        #pragma unroll
        for (int rr = 0; rr < 4; ++rr) {
            float sum = 0.f;
            #pragma unroll
            for (int t = 0; t < 8; ++t) {
                float p = __expf(s4[t][rr] * scale);
                uint u = __float_as_uint(p);
                uint r = (u + 0x7FFFu + ((u >> 16) & 1u)) >> 16;
                Ph[w][g * 4 + rr][t * 16 + c] = (ushort)r;
                sum += __uint_as_float(r << 16);
            }
            lpart[rr] += sum;
        }
        asm volatile("s_waitcnt lgkmcnt(0)" ::: "memory");

        #pragma unroll
        for (int kt = 0; kt < 4; ++kt) {
            short8 pah = *(const short8*)&Ph[w][c][kt * 32 + g * 8];
            #pragma unroll
            for (int T = 0; T < 2; ++T) {
                short8 vh = *(const short8*)&VTh[T * 16 + c][kt * 32 + g * 8];
                acc_o[T] = __builtin_amdgcn_mfma_f32_16x16x32_bf16(pah, vh, acc_o[T], 0, 0, 0);
            }
        }
    }

    #pragma unroll
    for (int rr = 0; rr < 4; ++rr) {
        float s = lpart[rr];
        s += __shfl_xor(s, 1);
        s += __shfl_xor(s, 2);
        s += __shfl_xor(s, 4);
        s += __shfl_xor(s, 8);
        lpart[rr] = s;
    }

    #pragma unroll
    for (int rr = 0; rr < 4; ++rr) {
        float inv = 1.0f / lpart[rr];
        int q = q0 + w * 16 + g * 4 + rr;
        #pragma unroll
        for (int T = 0; T < 2; ++T) {
            float v = acc_o[T][rr] * inv;
            size_t idx = (size_t)(b * 1024 + q) * 256 + h * 32 + T * 16 + c;
            ohi[idx] = rnd_bf16(v);
        }
    }
}

// ---------------- MFMA FFN1 128x64 BK=64, XCD-swizzled 1D grid ----------------
__global__ __launch_bounds__(256) void mfma_ffn1_12864(const ushort* __restrict__ Ah,
                                                       const ushort* __restrict__ W1h,
                                                       const float* __restrict__ b1l,
                                                       ushort* __restrict__ hh,
                                                       const int* __restrict__ ib,
                                                       int c0, int hFF, int NC) {
    int tileIdx, cj;
    xcd_map(blockIdx.x, NC, tileIdx, cj);
    if (tileIdx >= ib[IB_NTILES]) return;
    int e = ib[IB_TILE_E + tileIdx];
    int row0 = ib[IB_TILE_R0 + tileIdx];
    int rowend = ib[IB_TILE_RE + tileIdx];
    __shared__ ushort LAh[128][64], LBh[64][64];
    __shared__ int tok[128];
    int tid = threadIdx.x;
    if (tid < 128) {
        int sr = row0 + tid;
        tok[tid] = ib[IB_STOK + (sr < rowend ? sr : row0)];
    }
    __syncthreads();
    int w = tid >> 6, l = tid & 63, c = l & 15, G = l >> 4;
    int lr = l >> 3, sd = l & 7;
    int colbase = cj * 64;
    const ushort* Bh = W1h + (size_t)e * 262144 + (size_t)(c0 + colbase) * 256;
    size_t gaA[4]; ushort* dA[4];
    size_t gbB[2]; ushort* dB[2];
    #pragma unroll
    for (int i = 0; i < 4; ++i) {
        int r = i * 32 + w * 8 + lr;
        gaA[i] = (size_t)tok[r] * 256 + ((sd ^ (r & 7)) << 3);
        dA[i] = &LAh[i * 32 + w * 8][0];
    }
    #pragma unroll
    for (int i = 0; i < 2; ++i) {
        int r = i * 32 + w * 8 + lr;
        gbB[i] = (size_t)r * 256 + ((sd ^ (r & 7)) << 3);
        dB[i] = &LBh[i * 32 + w * 8][0];
    }
    f32x4 acc[2][4] = {};
    for (int k0 = 0; k0 < 256; k0 += 64) {
        #pragma unroll
        for (int i = 0; i < 4; ++i) gld16(&Ah[gaA[i] + k0], dA[i]);
        #pragma unroll
        for (int i = 0; i < 2; ++i) gld16(&Bh[gbB[i] + k0], dB[i]);
        __syncthreads();
        #pragma unroll
        for (int s = 0; s < 2; ++s) {
            int ar = w * 32 + c;
            short8 a_h[2];
            #pragma unroll
            for (int i = 0; i < 2; ++i) {
                int r = ar + i * 16;
                int sg = (((s << 2) | G) ^ (r & 7)) << 3;
                a_h[i] = *(const short8*)&LAh[r][sg];
            }
            #pragma unroll
            for (int j = 0; j < 4; ++j) {
                int r = j * 16 + c;
                int sg = (((s << 2) | G) ^ (r & 7)) << 3;
                short8 b_h = *(const short8*)&LBh[r][sg];
                #pragma unroll
                for (int i = 0; i < 2; ++i) {
                    acc[i][j] = __builtin_amdgcn_mfma_f32_16x16x32_bf16(a_h[i], b_h, acc[i][j], 0, 0, 0);
                }
            }
        }
        __syncthreads();
    }
    int rbase = row0 + w * 32 + G * 4;
    #pragma unroll
    for (int i = 0; i < 2; ++i) {
        #pragma unroll
        for (int j = 0; j < 4; ++j) {
            int cl = colbase + j * 16 + c;
            float bv = b1l[(size_t)e * FFD + c0 + cl];
            #pragma unroll
            for (int rr = 0; rr < 4; ++rr) {
                int sr = rbase + i * 16 + rr;
                if (sr < rowend) {
                    float v = gelu_exact(acc[i][j][rr] + bv);
                    hh[(size_t)sr * hFF + cl] = rnd_bf16(v);
                }
            }
        }
    }
}

// ---------------- MFMA FFN2 128x64 BK=64, XCD-swizzled 1D grid; OUT16 -> bf16 sout ----------------
template<bool OUT16>
__global__ __launch_bounds__(256) void mfma_ffn2_12864(const ushort* __restrict__ Ah,
                                                       const ushort* __restrict__ W2h,
                                                       const float* __restrict__ b2l,
                                                       float* __restrict__ soutf,
                                                       ushort* __restrict__ soutb,
                                                       const int* __restrict__ ib,
                                                       int c0, int hFF, int NC) {
    int tileIdx, cj;
    xcd_map(blockIdx.x, NC, tileIdx, cj);
    if (tileIdx >= ib[IB_NTILES]) return;
    int e = ib[IB_TILE_E + tileIdx];
    int row0 = ib[IB_TILE_R0 + tileIdx];
    int rowend = ib[IB_TILE_RE + tileIdx];
    __shared__ ushort LAh[128][64], LBh[64][64];
    int tid = threadIdx.x;
    int w = tid >> 6, l = tid & 63, c = l & 15, G = l >> 4;
    int lr = l >> 3, sd = l & 7;
    int colbase = cj * 64;
    const ushort* Bh = W2h + (size_t)e * 262144;
    size_t gaA[4]; ushort* dA[4];
    size_t gbB[2]; ushort* dB[2];
    #pragma unroll
    for (int i = 0; i < 4; ++i) {
        int r = i * 32 + w * 8 + lr;
        gaA[i] = (size_t)(row0 + r) * hFF + ((sd ^ (r & 7)) << 3);
        dA[i] = &LAh[i * 32 + w * 8][0];
    }
    #pragma unroll
    for (int i = 0; i < 2; ++i) {
        int r = i * 32 + w * 8 + lr;
        gbB[i] = (size_t)(colbase + r) * 1024 + c0 + ((sd ^ (r & 7)) << 3);
        dB[i] = &LBh[i * 32 + w * 8][0];
    }
    f32x4 acc[2][4] = {};
    for (int k0 = 0; k0 < hFF; k0 += 64) {
        #pragma unroll
        for (int i = 0; i < 4; ++i) gld16(&Ah[gaA[i] + k0], dA[i]);
        #pragma unroll
        for (int i = 0; i < 2; ++i) gld16(&Bh[gbB[i] + k0], dB[i]);
        __syncthreads();
        #pragma unroll
        for (int s = 0; s < 2; ++s) {
            int ar = w * 32 + c;
            short8 a_h[2];
            #pragma unroll
            for (int i = 0; i < 2; ++i) {
                int r = ar + i * 16;
                int sg = (((s << 2) | G) ^ (r & 7)) << 3;
                a_h[i] = *(const short8*)&LAh[r][sg];
            }
            #pragma unroll
            for (int j = 0; j < 4; ++j) {
                int r = j * 16 + c;
                int sg = (((s << 2) | G) ^ (r & 7)) << 3;
                short8 b_h = *(const short8*)&LBh[r][sg];
                #pragma unroll
                for (int i = 0; i < 2; ++i) {
                    acc[i][j] = __builtin_amdgcn_mfma_f32_16x16x32_bf16(a_h[i], b_h, acc[i][j], 0, 0, 0);
                }
            }
        }
        __syncthreads();
    }
    int rbase = row0 + w * 32 + G * 4;
    #pragma unroll
    for (int i = 0; i < 2; ++i) {
        #pragma unroll
        for (int j = 0; j < 4; ++j) {
            int n = colbase + j * 16 + c;
            float bv = b2l[(size_t)e * DIM + n];
            #pragma unroll
            for (int rr = 0; rr < 4; ++rr) {
                int sr = rbase + i * 16 + rr;
                if (sr < rowend) {
                    size_t idx = (size_t)sr * 256 + n;
                    if (OUT16) {
                        soutb[idx] = rnd_bf16(acc[i][j][rr] + bv);
                    } else {
                        if (c0 == 0) soutf[idx] = acc[i][j][rr] + bv;
                        else         soutf[idx] += acc[i][j][rr];
                    }
                }
            }
        }
    }
}

// ---------------- gate + top2 v3: LDS histogram, NO global atomics ----------------
__global__ __launch_bounds__(256) void gate_topk(const float* __restrict__ lnb,
                                                 const float* __restrict__ gw,
                                                 const float* __restrict__ gb,
                                                 float* __restrict__ gv, int* __restrict__ ib) {
    __shared__ int hist[8];
    int tid = threadIdx.x;
    if (tid < 8) hist[tid] = 0;
    __syncthreads();
    int grp = tid >> 3, ln8 = tid & 7;
    int t = blockIdx.x * 32 + grp;
    const float* x = lnb + (size_t)t * DIM + ln8 * 32;
    const float* wb = gw + (size_t)ln8 * 32 * 8;
    float g[8] = {};
    #pragma unroll
    for (int d4 = 0; d4 < 8; ++d4) {
        float4 xv = *(const float4*)&x[d4 * 4];
        const float* wr = wb + d4 * 32;
        float4 wa0 = *(const float4*)&wr[0],  wb0 = *(const float4*)&wr[4];
        float4 wa1 = *(const float4*)&wr[8],  wb1 = *(const float4*)&wr[12];
        float4 wa2 = *(const float4*)&wr[16], wb2 = *(const float4*)&wr[20];
        float4 wa3 = *(const float4*)&wr[24], wb3 = *(const float4*)&wr[28];
        g[0] += xv.x * wa0.x + xv.y * wa1.x + xv.z * wa2.x + xv.w * wa3.x;
        g[1] += xv.x * wa0.y + xv.y * wa1.y + xv.z * wa2.y + xv.w * wa3.y;
        g[2] += xv.x * wa0.z + xv.y * wa1.z + xv.z * wa2.z + xv.w * wa3.z;
        g[3] += xv.x * wa0.w + xv.y * wa1.w + xv.z * wa2.w + xv.w * wa3.w;
        g[4] += xv.x * wb0.x + xv.y * wb1.x + xv.z * wb2.x + xv.w * wb3.x;
        g[5] += xv.x * wb0.y + xv.y * wb1.y + xv.z * wb2.y + xv.w * wb3.y;
        g[6] += xv.x * wb0.z + xv.y * wb1.z + xv.z * wb2.z + xv.w * wb3.z;
        g[7] += xv.x * wb0.w + xv.y * wb1.w + xv.z * wb2.w + xv.w * wb3.w;
    }
    #pragma unroll
    for (int e = 0; e < 8; ++e) {
        g[e] += __shfl_xor(g[e], 1);
        g[e] += __shfl_xor(g[e], 2);
        g[e] += __shfl_xor(g[e], 4);
    }
    if (ln8 == 0) {
        #pragma unroll
        for (int e = 0; e < 8; ++e) g[e] += gb[e];
        int i0 = 0; float s0 = g[0];
        #pragma unroll
        for (int e = 1; e < 8; ++e) if (g[e] > s0) { s0 = g[e]; i0 = e; }
        int i1 = -1; float s1 = -1e30f;
        #pragma unroll
        for (int e = 0; e < 8; ++e) if (e != i0 && g[e] > s1) { s1 = g[e]; i1 = e; }
        float e1 = __expf(s1 - s0);
        float w0v = 1.0f / (1.0f + e1);
        float w1v = e1 / (1.0f + e1);
        gv[2 * t] = w0v; gv[2 * t + 1] = w1v;
        ib[IB_GIDX + 2 * t] = i0; ib[IB_GIDX + 2 * t + 1] = i1;
        atomicAdd(&hist[i0], 1);
        atomicAdd(&hist[i1], 1);
    }
    __syncthreads();
    if (tid < 8) ib[IB_BLKC + blockIdx.x * 8 + tid] = hist[tid];
}

// ---------------- scan: totals, offsets, per-block bases, tile table ----------------
__global__ __launch_bounds__(256) void scan_tiles(int* ib) {
    __shared__ int bc[2048], bb[2048];
    __shared__ int counts[8], offs[8], tstart[9];
    int tid = threadIdx.x;
    for (int i = tid; i < 2048; i += 256) bc[i] = ib[IB_BLKC + i];
    __syncthreads();
    if (tid < 8) {
        int run = 0;
        for (int b = 0; b < 256; ++b) {
            bb[b * 8 + tid] = run;
            run += bc[b * 8 + tid];
        }
        counts[tid] = run;
    }
    __syncthreads();
    if (tid == 0) {
        int off = 0, ts = 0;
        for (int e = 0; e < 8; ++e) {
            offs[e] = off;
            ib[IB_OFFS + e] = off;
            tstart[e] = ts;
            ib[IB_COUNTS + e] = counts[e];
            ts += (counts[e] + 127) >> 7;
            off += counts[e];
        }
        tstart[8] = ts;
        ib[IB_NTILES] = ts;
    }
    __syncthreads();
    for (int i = tid; i < 2048; i += 256)
        ib[IB_BLKB + i] = offs[i & 7] + bb[i];
    int total = tstart[8];
    for (int idx = tid; idx < total; idx += 256) {
        int e = 0;
        while (idx >= tstart[e + 1]) ++e;
        int i = idx - tstart[e];
        ib[IB_TILE_E + idx] = e;
        ib[IB_TILE_R0 + idx] = offs[e] + i * 128;
        int rem = counts[e] - i * 128;
        ib[IB_TILE_RE + idx] = offs[e] + i * 128 + (rem < 128 ? rem : 128);
    }
}

// ---------------- scatter to slots ----------------
__global__ __launch_bounds__(64) void scatter_slots(int* ib) {
    __shared__ int cnt8[8];
    int tid = threadIdx.x;
    if (tid < 8) cnt8[tid] = ib[IB_BLKB + blockIdx.x * 8 + tid];
    __syncthreads();
    int t = blockIdx.x * 32 + (tid >> 1);
    int k = tid & 1;
    int e = ib[IB_GIDX + 2 * t + k];
    int pos = atomicAdd(&cnt8[e], 1);
    ib[IB_STOK + pos] = t;
    ib[IB_SPOS + 2 * t + k] = pos;
}

// ---------------- gather (+ optional fused next-layer LN1; OUT16: bf16 sout) ----------------
template<bool WLN, bool OUT16>
__global__ __launch_bounds__(64) void moe_gather(float* __restrict__ xb,
                                                 const float* __restrict__ soutf,
                                                 const ushort* __restrict__ soutb,
                                                 const float* __restrict__ gv,
                                                 const int* __restrict__ ib,
                                                 ushort* __restrict__ ohi,
                                                 const float* __restrict__ g,
                                                 const float* __restrict__ b) {
    int t = blockIdx.x;
    int d = threadIdx.x * 4;
    int p0 = ib[IB_SPOS + 2 * t], p1 = ib[IB_SPOS + 2 * t + 1];
    float g0 = gv[2 * t], g1 = gv[2 * t + 1];
    float4 xv = *(float4*)&xb[(size_t)t * 256 + d];
    float s0x, s0y, s0z, s0w, s1x, s1y, s1z, s1w;
    if (OUT16) {
        uint2 a = *(const uint2*)&soutb[(size_t)p0 * 256 + d];
        uint2 bq = *(const uint2*)&soutb[(size_t)p1 * 256 + d];
        s0x = bf16_f32((ushort)(a.x & 0xFFFF));  s0y = bf16_f32((ushort)(a.x >> 16));
        s0z = bf16_f32((ushort)(a.y & 0xFFFF));  s0w = bf16_f32((ushort)(a.y >> 16));
        s1x = bf16_f32((ushort)(bq.x & 0xFFFF)); s1y = bf16_f32((ushort)(bq.x >> 16));
        s1z = bf16_f32((ushort)(bq.y & 0xFFFF)); s1w = bf16_f32((ushort)(bq.y >> 16));
    } else {
        float4 a = *(const float4*)&soutf[(size_t)p0 * 256 + d];
        float4 bq = *(const float4*)&soutf[(size_t)p1 * 256 + d];
        s0x = a.x; s0y = a.y; s0z = a.z; s0w = a.w;
        s1x = bq.x; s1y = bq.y; s1z = bq.z; s1w = bq.w;
    }
    xv.x += g0 * s0x + g1 * s1x;
    xv.y += g0 * s0y + g1 * s1y;
    xv.z += g0 * s0z + g1 * s1z;
    xv.w += g0 * s0w + g1 * s1w;
    *(float4*)&xb[(size_t)t * 256 + d] = xv;
    if (WLN) {
        float s = xv.x + xv.y + xv.z + xv.w;
        #pragma unroll
        for (int off = 32; off; off >>= 1) s += __shfl_xor(s, off);
        float mean = s * (1.0f / 256.0f);
        float dx = xv.x - mean, dy = xv.y - mean, dz = xv.z - mean, dw = xv.w - mean;
        float vs = dx * dx + dy * dy + dz * dz + dw * dw;
        #pragma unroll
        for (int off = 32; off; off >>= 1) vs += __shfl_xor(vs, off);
        float inv = rsqrtf(vs * (1.0f / 256.0f) + 1e-5f);
        float4 gg = *(const float4*)&g[d];
        float4 bb = *(const float4*)&b[d];
        float o0 = dx * inv * gg.x + bb.x;
        float o1 = dy * inv * gg.y + bb.y;
        float o2 = dz * inv * gg.z + bb.z;
        float o3 = dw * inv * gg.w + bb.w;
        uint2 ph;
        ph.x = (uint)rnd_bf16(o0) | ((uint)rnd_bf16(o1) << 16);
        ph.y = (uint)rnd_bf16(o2) | ((uint)rnd_bf16(o3) << 16);
        *(uint2*)&ohi[(size_t)t * 256 + d] = ph;
    }
}

// ---------------- pooling ----------------
__global__ __launch_bounds__(256) void pool1(const float* __restrict__ xb, float* __restrict__ pp) {
    int b = blockIdx.x, ch = blockIdx.y, d = threadIdx.x;
    float s = 0.0f;
    for (int i = 0; i < 32; ++i) s += xb[((size_t)b * 1024 + ch * 32 + i) * 256 + d];
    pp[(size_t)(b * 32 + ch) * 256 + d] = s;
}
__global__ __launch_bounds__(256) void pool2(const float* __restrict__ pp, float* __restrict__ pool) {
    int b = blockIdx.x, d = threadIdx.x;
    float s = 0.0f;
    for (int c = 0; c < 32; ++c) s += pp[(size_t)(b * 32 + c) * 256 + d];
    pool[(size_t)b * 256 + d] = s * (1.0f / 1024.0f);
}

// ---------------- head ----------------
__global__ __launch_bounds__(256) void head_kernel(const float* __restrict__ pool,
                                                   const float* __restrict__ hw,
                                                   const float* __restrict__ hb,
                                                   float* __restrict__ out) {
    __shared__ float P[2048];
    int tid = threadIdx.x;
    for (int i = tid; i < 2048; i += 256) P[i] = pool[i];
    __syncthreads();
    int j = blockIdx.x * 256 + tid;
    if (j >= NOUT) return;
    float acc[8] = {};
    for (int d = 0; d < 256; ++d) {
        float w = hw[(size_t)d * NOUT + j];
        #pragma unroll
        for (int b = 0; b < 8; ++b) acc[b] += P[b * 256 + d] * w;
    }
    #pragma unroll
    for (int b = 0; b < 8; ++b) out[(size_t)b * NOUT + j] = acc[b] + hb[j];
}

extern "C" void kernel_launch(void* const* d_in, const int* in_sizes, int n_in,
                              void* d_out, int out_size, void* d_ws, size_t ws_size,
                              hipStream_t stream) {
    const float* x      = (const float*)d_in[0];
    const float* qkv_w  = (const float*)d_in[1];
    const float* qkv_b  = (const float*)d_in[2];
    const float* attn_w = (const float*)d_in[3];
    const float* attn_b = (const float*)d_in[4];
    const float* gate_w = (const float*)d_in[5];
    const float* gate_b = (const float*)d_in[6];
    const float* e_w1   = (const float*)d_in[7];
    const float* e_b1   = (const float*)d_in[8];
    const float* e_w2   = (const float*)d_in[9];
    const float* e_b2   = (const float*)d_in[10];
    const float* ln1_g  = (const float*)d_in[11];
    const float* ln1_b  = (const float*)d_in[12];
    const float* ln2_g  = (const float*)d_in[13];
    const float* ln2_b  = (const float*)d_in[14];
    const float* head_w = (const float*)d_in[15];
    const float* head_b = (const float*)d_in[16];
    float* out = (float*)d_out;
    float* wsf = (float*)d_ws;

    float* xb   = wsf + WS_X;
    float* lnb  = wsf + WS_LN;
    float* sobf = wsf + WS_SOUT;
    ushort* sobb = (ushort*)(wsf + WS_SOUT);
    float* gv   = wsf + WS_GV;
    float* pp   = wsf + WS_PP;
    float* pool = wsf + WS_POOL;
    int*   ib   = (int*)(wsf + WS_INT);

    ushort* qkvsh = (ushort*)(wsf + WS_QKV);
    ushort* wT    = (ushort*)(wsf + WS_QKV);
    ushort* w1th  = wT;
    ushort* w2th  = wT + 4194304;

    ushort* vth = (ushort*)(wsf + WS_H);

    ushort* u16  = (ushort*)(wsf + WS_U16);
    ushort* lnh  = u16;
    ushort* qwh  = u16 + 4194304;
    ushort* awh  = u16 + 4587520;

    // ---- adaptive FFN chunking (h is bf16-only: NSLOT*hFF*2 bytes) ----
    size_t base_bytes = (size_t)WS_BIG * 4;
    int hFF = 256;
    if (ws_size >= base_bytes + (size_t)NSLOT * 1024 * 2)      hFF = 1024;
    else if (ws_size >= base_bytes + (size_t)NSLOT * 512 * 2)  hFF = 512;
    ushort* hh = (hFF == 256) ? (ushort*)(wsf + WS_H) : (ushort*)(wsf + WS_BIG);
    int NCC = 1024 / hFF;

    hipMemcpyAsync(xb, x, (size_t)TOK * DIM * sizeof(float), hipMemcpyDeviceToDevice, stream);

    for (int l = 0; l < NL; ++l) {
        // --- attention block ---
        if (l == 0)
            ln_split<false><<<TOK / 4, 256, 0, stream>>>(xb, nullptr, lnh, ln1_g, ln1_b);
        st_attn_weights<<<dim3(8, 32), 256, 0, stream>>>(
            qkv_w + (size_t)l * DIM * 3 * DIM, attn_w + (size_t)l * DIM * DIM, qwh, awh);
        mfma_dense128x64<3><<<64 * 12, 256, 0, stream>>>(
            lnh, qwh, qkv_b + (size_t)l * 3 * DIM, nullptr, qkvsh, 768, 12);
        vt_kernel<<<dim3(32, 64), 256, 0, stream>>>(qkvsh, vth);
        attention_mfma<<<dim3(16, NH, 8), 256, 0, stream>>>(qkvsh, vth, lnh);
        mfma_dense128x64<1><<<64 * 4, 256, 0, stream>>>(
            lnh, awh, attn_b + (size_t)l * DIM, xb, nullptr, 256, 4);

        // --- MoE block ---
        ln_split<true><<<TOK / 4, 256, 0, stream>>>(xb, lnb, lnh, ln2_g, ln2_b);
        st_expert_weights<<<dim3(512, 8), 256, 0, stream>>>(
            e_w1 + (size_t)l * NE * DIM * FFD, e_w2 + (size_t)l * NE * FFD * DIM, w1th, w2th);
        gate_topk<<<TOK / 32, 256, 0, stream>>>(
            lnb, gate_w + (size_t)l * DIM * NE, gate_b + (size_t)l * NE, gv, ib);
        scan_tiles<<<1, 256, 0, stream>>>(ib);
        scatter_slots<<<TOK / 32, 64, 0, stream>>>(ib);
        if (NCC == 1) {
            mfma_ffn1_12864<<<136 * 16, 256, 0, stream>>>(
                lnh, w1th, e_b1 + (size_t)l * NE * FFD, hh, ib, 0, 1024, 16);
            mfma_ffn2_12864<true><<<136 * 4, 256, 0, stream>>>(
                hh, w2th, e_b2 + (size_t)l * NE * DIM, nullptr, sobb, ib, 0, 1024, 4);
            if (l + 1 < NL)
                moe_gather<true, true><<<TOK, 64, 0, stream>>>(xb, nullptr, sobb, gv, ib, lnh, ln1_g, ln1_b);
            else
                moe_gather<false, true><<<TOK, 64, 0, stream>>>(xb, nullptr, sobb, gv, ib, nullptr, nullptr, nullptr);
        } else {
            for (int c = 0; c < NCC; ++c) {
                mfma_ffn1_12864<<<136 * (hFF / 64), 256, 0, stream>>>(
                    lnh, w1th, e_b1 + (size_t)l * NE * FFD, hh, ib, c * hFF, hFF, hFF / 64);
                mfma_ffn2_12864<false><<<136 * 4, 256, 0, stream>>>(
                    hh, w2th, e_b2 + (size_t)l * NE * DIM, sobf, nullptr, ib, c * hFF, hFF, 4);
            }
            if (l + 1 < NL)
                moe_gather<true, false><<<TOK, 64, 0, stream>>>(xb, sobf, nullptr, gv, ib, lnh, ln1_g, ln1_b);
            else
                moe_gather<false, false><<<TOK, 64, 0, stream>>>(xb, sobf, nullptr, gv, ib, nullptr, nullptr, nullptr);
        }
    }

    pool1<<<dim3(8, 32), 256, 0, stream>>>(xb, pp);
    pool2<<<8, 256, 0, stream>>>(pp, pool);
    head_kernel<<<4, 256, 0, stream>>>(pool, head_w, head_b, out);
}